// Round 1
// baseline (2528.982 us; speedup 1.0000x reference)
//
#include <hip/hip_runtime.h>
#include <math.h>

#define N_USERS    200000
#define N_ITEMS    50000
#define N_ENTITIES 150000
#define N_EDGES    2000000
#define N_INTER    1000000
#define D          64

__device__ __forceinline__ float wave_sum64(float v) {
#pragma unroll
    for (int off = 32; off > 0; off >>= 1) v += __shfl_xor(v, off, 64);
    return v;
}

// One wave per edge: agg[head] += ent[tail] * wrel[type]; cnt[head] += 1
__global__ void edge_scatter_k(const float* __restrict__ ent,
                               const float* __restrict__ wrel,
                               const int* __restrict__ head,
                               const int* __restrict__ tail,
                               const int* __restrict__ type,
                               float* __restrict__ agg,
                               int* __restrict__ cnt) {
    int e = blockIdx.x * 4 + (threadIdx.x >> 6);
    if (e >= N_EDGES) return;
    int lane = threadIdx.x & 63;
    int h = head[e], t = tail[e], r = type[e];
    float v = ent[t * D + lane] * wrel[r * D + lane];
    atomicAdd(&agg[h * D + lane], v);
    if (lane == 0) atomicAdd(&cnt[h], 1);
}

// One wave per interaction: iint[col] += usr[row]; cnt_item[col] += 1
__global__ void inter_scatter_k(const float* __restrict__ usr,
                                const int* __restrict__ mrow,
                                const int* __restrict__ mcol,
                                float* __restrict__ iint,
                                int* __restrict__ cnt_item) {
    int i = blockIdx.x * 4 + (threadIdx.x >> 6);
    if (i >= N_INTER) return;
    int lane = threadIdx.x & 63;
    int r = mrow[i], c = mcol[i];
    float v = usr[r * D + lane];
    atomicAdd(&iint[c * D + lane], v);
    if (lane == 0) atomicAdd(&cnt_item[c], 1);
}

// One wave per interaction: uagg[row] += ifus[col]
__global__ void user_scatter_k(const float* __restrict__ ifus,
                               const int* __restrict__ mrow,
                               const int* __restrict__ mcol,
                               float* __restrict__ uagg) {
    int i = blockIdx.x * 4 + (threadIdx.x >> 6);
    if (i >= N_INTER) return;
    int lane = threadIdx.x & 63;
    int r = mrow[i], c = mcol[i];
    float v = ifus[c * D + lane];
    atomicAdd(&uagg[r * D + lane], v);
}

// Per item row: mean -> gate -> fusion -> norms -> residuals.
// One wave per item, g1/g2 staged in LDS (stride 65 to kill bank conflicts).
__global__ void fuse_k(const float* __restrict__ agg,
                       const int* __restrict__ cnt_ent,
                       const float* __restrict__ iint,
                       const int* __restrict__ cnt_item,
                       const float* __restrict__ g1,
                       const float* __restrict__ g2,
                       float* __restrict__ ifus,
                       float* __restrict__ ent_cur,
                       float* __restrict__ ent_res,
                       float* __restrict__ kg_res,
                       float* __restrict__ int_res) {
    __shared__ float g1s[64 * 65];
    __shared__ float g2s[64 * 65];
    for (int idx = threadIdx.x; idx < 64 * 64; idx += blockDim.x) {
        int r = idx >> 6, c = idx & 63;
        g1s[r * 65 + c] = g1[idx];
        g2s[r * 65 + c] = g2[idx];
    }
    __syncthreads();

    int lane = threadIdx.x & 63;
    int wid = blockIdx.x * (blockDim.x >> 6) + (threadIdx.x >> 6);
    int nw = gridDim.x * (blockDim.x >> 6);
    int jb = lane * 65;

    for (int i = wid; i < N_ITEMS; i += nw) {
        float ckg = fmaxf((float)cnt_ent[i], 1.0f);
        float cii = fmaxf((float)cnt_item[i], 1.0f);
        float kg = agg[i * D + lane] / ckg;
        float ii = iint[i * D + lane] / cii;

        // y[lane] = sum_k kg[k]*g1[lane,k] + ii[k]*g2[lane,k]
        float y = 0.f;
#pragma unroll
        for (int k = 0; k < 64; ++k) {
            y = fmaf(__shfl(kg, k, 64), g1s[jb + k], y);
            y = fmaf(__shfl(ii, k, 64), g2s[jb + k], y);
        }
        float gi = 1.0f / (1.0f + __expf(-y));
        float fus = gi * kg + (1.0f - gi) * ii;
        ifus[i * D + lane] = fus;

        float sf = wave_sum64(fus * fus);
        float sk = wave_sum64(kg * kg);
        float si = wave_sum64(ii * ii);
        float fn = fus / fmaxf(sqrtf(sf), 1e-12f);
        ent_cur[i * D + lane] = fn;
        ent_res[i * D + lane] += fn;
        kg_res[i * D + lane] += kg / fmaxf(sqrtf(sk), 1e-12f);
        int_res[i * D + lane] += ii / fmaxf(sqrtf(si), 1e-12f);
    }
}

// Non-item entities: mean -> l2norm -> ent_cur + ent_res. One wave per row.
__global__ void att_norm_k(const float* __restrict__ agg,
                           const int* __restrict__ cnt_ent,
                           float* __restrict__ ent_cur,
                           float* __restrict__ ent_res) {
    int r = blockIdx.x * 4 + (threadIdx.x >> 6);
    if (r >= N_ENTITIES - N_ITEMS) return;
    int lane = threadIdx.x & 63;
    int row = N_ITEMS + r;
    float c = fmaxf((float)cnt_ent[row], 1.0f);
    float v = agg[row * D + lane] / c;
    float s = wave_sum64(v * v);
    float vn = v / fmaxf(sqrtf(s), 1e-12f);
    ent_cur[row * D + lane] = vn;
    ent_res[row * D + lane] += vn;
}

// Users: l2norm(user_agg) -> usr_cur + usr_res. One wave per row.
__global__ void user_norm_k(const float* __restrict__ uagg,
                            float* __restrict__ usr_cur,
                            float* __restrict__ usr_res) {
    int u = blockIdx.x * 4 + (threadIdx.x >> 6);
    if (u >= N_USERS) return;
    int lane = threadIdx.x & 63;
    float v = uagg[u * D + lane];
    float s = wave_sum64(v * v);
    float vn = v / fmaxf(sqrtf(s), 1e-12f);
    usr_cur[u * D + lane] = vn;
    usr_res[u * D + lane] += vn;
}

extern "C" void kernel_launch(void* const* d_in, const int* in_sizes, int n_in,
                              void* d_out, int out_size, void* d_ws, size_t ws_size,
                              hipStream_t stream) {
    const float* user_emb   = (const float*)d_in[0];
    const float* entity_emb = (const float*)d_in[1];
    const float* wrel       = (const float*)d_in[2];
    const float* g1         = (const float*)d_in[3];
    const float* g2         = (const float*)d_in[4];
    const int*   edge_head  = (const int*)d_in[5];
    const int*   edge_tail  = (const int*)d_in[6];
    const int*   edge_type  = (const int*)d_in[7];
    const int*   mat_row    = (const int*)d_in[8];
    const int*   mat_col    = (const int*)d_in[9];

    const size_t ENT_SZ = (size_t)N_ENTITIES * D;  //  9,600,000
    const size_t USR_SZ = (size_t)N_USERS * D;     // 12,800,000
    const size_t ITM_SZ = (size_t)N_ITEMS * D;     //  3,200,000

    float* out     = (float*)d_out;
    float* ent_res = out;
    float* usr_res = out + ENT_SZ;
    float* kg_res  = out + ENT_SZ + USR_SZ;
    float* int_res = out + ENT_SZ + USR_SZ + ITM_SZ;

    // workspace layout (floats):
    float* ws      = (float*)d_ws;
    float* ent_cur = ws;                       // 9.6M
    float* usr_cur = ws + ENT_SZ;              // 12.8M
    float* agg     = ws + ENT_SZ + USR_SZ;     // 9.6M  (entity_agg)
    float* iint    = agg + ENT_SZ;             // 3.2M  (item_int_agg)
    float* uagg    = agg;                      // 12.8M, aliases agg+iint (disjoint lifetime)
    float* ifus    = agg + ENT_SZ + ITM_SZ;    // 3.2M  (item_fusion)
    int*   cnt_ent  = (int*)(ifus + ITM_SZ);   // 150,000
    int*   cnt_item = cnt_ent + N_ENTITIES;    //  50,000

    // init: residuals and current embeddings
    hipMemcpyAsync(ent_cur, entity_emb, ENT_SZ * sizeof(float), hipMemcpyDeviceToDevice, stream);
    hipMemcpyAsync(usr_cur, user_emb,   USR_SZ * sizeof(float), hipMemcpyDeviceToDevice, stream);
    hipMemcpyAsync(ent_res, entity_emb, ENT_SZ * sizeof(float), hipMemcpyDeviceToDevice, stream);
    hipMemcpyAsync(usr_res, user_emb,   USR_SZ * sizeof(float), hipMemcpyDeviceToDevice, stream);
    hipMemsetAsync(kg_res, 0, 2 * ITM_SZ * sizeof(float), stream);  // kg_res + int_res

    for (int hop = 0; hop < 2; ++hop) {
        // zero entity_agg + item_int_agg (contiguous) and both count arrays
        hipMemsetAsync(agg, 0, (ENT_SZ + ITM_SZ) * sizeof(float), stream);
        hipMemsetAsync(cnt_ent, 0, (N_ENTITIES + N_ITEMS) * sizeof(int), stream);

        edge_scatter_k<<<(N_EDGES + 3) / 4, 256, 0, stream>>>(
            ent_cur, wrel, edge_head, edge_tail, edge_type, agg, cnt_ent);
        inter_scatter_k<<<(N_INTER + 3) / 4, 256, 0, stream>>>(
            usr_cur, mat_row, mat_col, iint, cnt_item);
        fuse_k<<<1024, 256, 0, stream>>>(
            agg, cnt_ent, iint, cnt_item, g1, g2, ifus, ent_cur, ent_res, kg_res, int_res);
        att_norm_k<<<(N_ENTITIES - N_ITEMS + 3) / 4, 256, 0, stream>>>(
            agg, cnt_ent, ent_cur, ent_res);

        // after att_norm, agg/iint are dead -> reuse region as user_agg
        hipMemsetAsync(uagg, 0, USR_SZ * sizeof(float), stream);
        user_scatter_k<<<(N_INTER + 3) / 4, 256, 0, stream>>>(
            ifus, mat_row, mat_col, uagg);
        user_norm_k<<<(N_USERS + 3) / 4, 256, 0, stream>>>(
            uagg, usr_cur, usr_res);
    }
}

// Round 2
// 1706.889 us; speedup vs baseline: 1.4816x; 1.4816x over previous
//
#include <hip/hip_runtime.h>
#include <math.h>

#define N_USERS    200000
#define N_ITEMS    50000
#define N_ENTITIES 150000
#define N_EDGES    2000000
#define N_INTER    1000000
#define D          64
#define NTOT       (N_EDGES + 2 * N_INTER)

__device__ __forceinline__ float wave_sum64(float v) {
#pragma unroll
    for (int off = 32; off > 0; off >>= 1) v += __shfl_xor(v, off, 64);
    return v;
}

// ---- CSR build: histogram over all three key arrays (grid-stride) ----
__global__ void hist_k(const int* __restrict__ head,
                       const int* __restrict__ mcol,
                       const int* __restrict__ mrow,
                       int* __restrict__ eh, int* __restrict__ ch, int* __restrict__ rh) {
    for (int i = blockIdx.x * blockDim.x + threadIdx.x; i < NTOT;
         i += gridDim.x * blockDim.x) {
        if (i < N_EDGES) atomicAdd(&eh[head[i]], 1);
        else if (i < N_EDGES + N_INTER) atomicAdd(&ch[mcol[i - N_EDGES]], 1);
        else atomicAdd(&rh[mrow[i - N_EDGES - N_INTER]], 1);
    }
}

// ---- single-block exclusive scan; blockIdx selects which array ----
__global__ void scan_k(const int* __restrict__ eh, const int* __restrict__ ch,
                       const int* __restrict__ rh,
                       int* __restrict__ es, int* __restrict__ cs, int* __restrict__ rs,
                       int* __restrict__ ec, int* __restrict__ cc, int* __restrict__ rc) {
    const int* h; int* s; int* c; int n;
    if (blockIdx.x == 0)      { h = eh; s = es; c = ec; n = N_ENTITIES; }
    else if (blockIdx.x == 1) { h = ch; s = cs; c = cc; n = N_ITEMS; }
    else                      { h = rh; s = rs; c = rc; n = N_USERS; }
    __shared__ int ss[1024];
    int t = threadIdx.x;
    int C = (n + 1023) >> 10;
    int lo = t * C; if (lo > n) lo = n;
    int hi = lo + C; if (hi > n) hi = n;
    int sum = 0;
    for (int i = lo; i < hi; ++i) sum += h[i];
    ss[t] = sum;
    __syncthreads();
    for (int off = 1; off < 1024; off <<= 1) {
        int v = (t >= off) ? ss[t - off] : 0;
        __syncthreads();
        ss[t] += v;
        __syncthreads();
    }
    int run = (t == 0) ? 0 : ss[t - 1];
    for (int i = lo; i < hi; ++i) { int hv = h[i]; s[i] = run; c[i] = run; run += hv; }
    if (t == 1023) s[n] = ss[1023];
}

// ---- permute: place edges/interactions into segment-sorted arrays ----
__global__ void permute_k(const int* __restrict__ head, const int* __restrict__ tail,
                          const int* __restrict__ type,
                          const int* __restrict__ mcol, const int* __restrict__ mrow,
                          int* __restrict__ ec, int* __restrict__ cc, int* __restrict__ rc,
                          int* __restrict__ e_sorted, int* __restrict__ i_srow,
                          int* __restrict__ i_scol) {
    for (int i = blockIdx.x * blockDim.x + threadIdx.x; i < NTOT;
         i += gridDim.x * blockDim.x) {
        if (i < N_EDGES) {
            int h = head[i];
            int pos = atomicAdd(&ec[h], 1);
            e_sorted[pos] = tail[i] | (type[i] << 18);   // 150K < 2^18, type < 32
        } else if (i < N_EDGES + N_INTER) {
            int j = i - N_EDGES;
            int c = mcol[j];
            int pos = atomicAdd(&cc[c], 1);
            i_srow[pos] = mrow[j];
        } else {
            int j = i - N_EDGES - N_INTER;
            int r = mrow[j];
            int pos = atomicAdd(&rc[r], 1);
            i_scol[pos] = mcol[j];
        }
    }
}

// ---- per-entity aggregation (gather). One wave per head row. ----
// items: write mean into agg. att rows: fold l2-norm; hop0 writes ent_cur,
// last hop writes only ent_res (+=).
__global__ void edge_agg_k(const float* __restrict__ ent,
                           const float* __restrict__ wrel,
                           const int* __restrict__ es,
                           const int* __restrict__ e_sorted,
                           float* __restrict__ agg,
                           float* __restrict__ ent_cur,
                           float* __restrict__ ent_res,
                           int last_hop) {
    __shared__ float wl[32 * 64];
    for (int idx = threadIdx.x; idx < 32 * 64; idx += blockDim.x) wl[idx] = wrel[idx];
    __syncthreads();
    int lane = threadIdx.x & 63;
    int wid = blockIdx.x * (blockDim.x >> 6) + (threadIdx.x >> 6);
    int nw = gridDim.x * (blockDim.x >> 6);
    for (int h = wid; h < N_ENTITIES; h += nw) {
        int beg = es[h], end = es[h + 1];
        float a0 = 0.f, a1 = 0.f;
        for (int j0 = beg; j0 < end; j0 += 64) {
            int p = (j0 + lane < end) ? e_sorted[j0 + lane] : 0;
            int m = end - j0; if (m > 64) m = 64;
            int k = 0;
            for (; k + 1 < m; k += 2) {
                int p0 = __shfl(p, k, 64), p1 = __shfl(p, k + 1, 64);
                a0 = fmaf(ent[(size_t)(p0 & 0x3FFFF) * D + lane], wl[(p0 >> 18) * D + lane], a0);
                a1 = fmaf(ent[(size_t)(p1 & 0x3FFFF) * D + lane], wl[(p1 >> 18) * D + lane], a1);
            }
            if (k < m) {
                int p0 = __shfl(p, k, 64);
                a0 = fmaf(ent[(size_t)(p0 & 0x3FFFF) * D + lane], wl[(p0 >> 18) * D + lane], a0);
            }
        }
        float acc = a0 + a1;
        if (h < N_ITEMS) {
            int d = end - beg;
            agg[(size_t)h * D + lane] = acc / (float)(d > 0 ? d : 1);
        } else {
            // l2norm(mean) == l2norm(sum): scale-invariant
            float s = wave_sum64(acc * acc);
            float vn = acc / fmaxf(sqrtf(s), 1e-12f);
            if (!last_hop) ent_cur[(size_t)h * D + lane] = vn;
            ent_res[(size_t)h * D + lane] += vn;
        }
    }
}

// ---- per-item interaction mean (gather). One wave per item. ----
__global__ void inter_agg_k(const float* __restrict__ usr,
                            const int* __restrict__ cs,
                            const int* __restrict__ i_srow,
                            float* __restrict__ iint) {
    int lane = threadIdx.x & 63;
    int wid = blockIdx.x * (blockDim.x >> 6) + (threadIdx.x >> 6);
    int nw = gridDim.x * (blockDim.x >> 6);
    for (int c = wid; c < N_ITEMS; c += nw) {
        int beg = cs[c], end = cs[c + 1];
        float a0 = 0.f, a1 = 0.f;
        for (int j0 = beg; j0 < end; j0 += 64) {
            int p = (j0 + lane < end) ? i_srow[j0 + lane] : 0;
            int m = end - j0; if (m > 64) m = 64;
            int k = 0;
            for (; k + 1 < m; k += 2) {
                int p0 = __shfl(p, k, 64), p1 = __shfl(p, k + 1, 64);
                a0 += usr[(size_t)p0 * D + lane];
                a1 += usr[(size_t)p1 * D + lane];
            }
            if (k < m) {
                int p0 = __shfl(p, k, 64);
                a0 += usr[(size_t)p0 * D + lane];
            }
        }
        float acc = a0 + a1;
        int d = end - beg;
        iint[(size_t)c * D + lane] = acc / (float)(d > 0 ? d : 1);
    }
}

// ---- gate + fusion + norms + residuals. agg/iint are already means. ----
// ifus may alias iint (per-thread read-before-write at same address).
__global__ void fuse_k(const float* __restrict__ agg,
                       const float* __restrict__ iint,
                       const float* __restrict__ g1,
                       const float* __restrict__ g2,
                       float* __restrict__ ifus,
                       float* __restrict__ ent_cur,
                       float* __restrict__ ent_res,
                       float* __restrict__ kg_res,
                       float* __restrict__ int_res) {
    __shared__ float g1s[64 * 65];
    __shared__ float g2s[64 * 65];
    for (int idx = threadIdx.x; idx < 64 * 64; idx += blockDim.x) {
        int r = idx >> 6, c = idx & 63;
        g1s[r * 65 + c] = g1[idx];
        g2s[r * 65 + c] = g2[idx];
    }
    __syncthreads();
    int lane = threadIdx.x & 63;
    int wid = blockIdx.x * (blockDim.x >> 6) + (threadIdx.x >> 6);
    int nw = gridDim.x * (blockDim.x >> 6);
    int jb = lane * 65;
    for (int i = wid; i < N_ITEMS; i += nw) {
        float kg = agg[(size_t)i * D + lane];
        float ii = iint[(size_t)i * D + lane];
        float y = 0.f;
#pragma unroll
        for (int k = 0; k < 64; ++k) {
            y = fmaf(__shfl(kg, k, 64), g1s[jb + k], y);
            y = fmaf(__shfl(ii, k, 64), g2s[jb + k], y);
        }
        float gi = 1.0f / (1.0f + __expf(-y));
        float fus = gi * kg + (1.0f - gi) * ii;
        ifus[(size_t)i * D + lane] = fus;
        float sf = wave_sum64(fus * fus);
        float sk = wave_sum64(kg * kg);
        float si = wave_sum64(ii * ii);
        float fn = fus / fmaxf(sqrtf(sf), 1e-12f);
        ent_cur[(size_t)i * D + lane] = fn;
        ent_res[(size_t)i * D + lane] += fn;
        kg_res[(size_t)i * D + lane] += kg / fmaxf(sqrtf(sk), 1e-12f);
        int_res[(size_t)i * D + lane] += ii / fmaxf(sqrtf(si), 1e-12f);
    }
}

// ---- per-user segment sum of item_fusion + l2 norm, fused. ----
__global__ void user_agg_k(const float* __restrict__ ifus,
                           const int* __restrict__ rs,
                           const int* __restrict__ i_scol,
                           float* __restrict__ usr_cur,
                           float* __restrict__ usr_res) {
    int lane = threadIdx.x & 63;
    int wid = blockIdx.x * (blockDim.x >> 6) + (threadIdx.x >> 6);
    int nw = gridDim.x * (blockDim.x >> 6);
    for (int u = wid; u < N_USERS; u += nw) {
        int beg = rs[u], end = rs[u + 1];
        float a0 = 0.f, a1 = 0.f;
        for (int j0 = beg; j0 < end; j0 += 64) {
            int p = (j0 + lane < end) ? i_scol[j0 + lane] : 0;
            int m = end - j0; if (m > 64) m = 64;
            int k = 0;
            for (; k + 1 < m; k += 2) {
                int p0 = __shfl(p, k, 64), p1 = __shfl(p, k + 1, 64);
                a0 += ifus[(size_t)p0 * D + lane];
                a1 += ifus[(size_t)p1 * D + lane];
            }
            if (k < m) {
                int p0 = __shfl(p, k, 64);
                a0 += ifus[(size_t)p0 * D + lane];
            }
        }
        float acc = a0 + a1;
        float s = wave_sum64(acc * acc);
        float vn = acc / fmaxf(sqrtf(s), 1e-12f);
        usr_cur[(size_t)u * D + lane] = vn;
        usr_res[(size_t)u * D + lane] += vn;
    }
}

extern "C" void kernel_launch(void* const* d_in, const int* in_sizes, int n_in,
                              void* d_out, int out_size, void* d_ws, size_t ws_size,
                              hipStream_t stream) {
    const float* user_emb   = (const float*)d_in[0];
    const float* entity_emb = (const float*)d_in[1];
    const float* wrel       = (const float*)d_in[2];
    const float* g1         = (const float*)d_in[3];
    const float* g2         = (const float*)d_in[4];
    const int*   edge_head  = (const int*)d_in[5];
    const int*   edge_tail  = (const int*)d_in[6];
    const int*   edge_type  = (const int*)d_in[7];
    const int*   mat_row    = (const int*)d_in[8];
    const int*   mat_col    = (const int*)d_in[9];

    const size_t ENT_SZ = (size_t)N_ENTITIES * D;  //  9.6M
    const size_t USR_SZ = (size_t)N_USERS * D;     // 12.8M
    const size_t ITM_SZ = (size_t)N_ITEMS * D;     //  3.2M

    float* out     = (float*)d_out;
    float* ent_res = out;
    float* usr_res = out + ENT_SZ;
    float* kg_res  = out + ENT_SZ + USR_SZ;
    float* int_res = out + ENT_SZ + USR_SZ + ITM_SZ;

    // workspace layout
    float* ws      = (float*)d_ws;
    float* ent_cur = ws;                        // 9.6M f
    float* usr_cur = ent_cur + ENT_SZ;          // 12.8M f
    float* agg     = usr_cur + USR_SZ;          // 3.2M f (item kg means)
    float* iint    = agg + ITM_SZ;              // 3.2M f (aliases ifus)
    float* ifus    = iint;                      // alias: read-before-write per thread
    int*   e_hist  = (int*)(iint + ITM_SZ);     // 150000  } contiguous for
    int*   c_hist  = e_hist + N_ENTITIES;       //  50000  } one memset
    int*   r_hist  = c_hist + N_ITEMS;          // 200000  }
    int*   e_starts = r_hist + N_USERS;         // 150001
    int*   c_starts = e_starts + N_ENTITIES + 1;//  50001
    int*   r_starts = c_starts + N_ITEMS + 1;   // 200001
    int*   e_curs   = r_starts + N_USERS + 1;   // 150000
    int*   c_curs   = e_curs + N_ENTITIES;      //  50000
    int*   r_curs   = c_curs + N_ITEMS;         // 200000
    int*   e_sorted = r_curs + N_USERS;         // 2,000,000 (tail | type<<18)
    int*   i_srow   = e_sorted + N_EDGES;       // 1,000,000
    int*   i_scol   = i_srow + N_INTER;         // 1,000,000

    // init outputs + histograms
    hipMemcpyAsync(ent_res, entity_emb, ENT_SZ * sizeof(float), hipMemcpyDeviceToDevice, stream);
    hipMemcpyAsync(usr_res, user_emb,   USR_SZ * sizeof(float), hipMemcpyDeviceToDevice, stream);
    hipMemsetAsync(kg_res, 0, 2 * ITM_SZ * sizeof(float), stream);
    hipMemsetAsync(e_hist, 0, (N_ENTITIES + N_ITEMS + N_USERS) * sizeof(int), stream);

    // CSR build (hop-invariant)
    hist_k<<<4096, 256, 0, stream>>>(edge_head, mat_col, mat_row, e_hist, c_hist, r_hist);
    scan_k<<<3, 1024, 0, stream>>>(e_hist, c_hist, r_hist,
                                   e_starts, c_starts, r_starts,
                                   e_curs, c_curs, r_curs);
    permute_k<<<4096, 256, 0, stream>>>(edge_head, edge_tail, edge_type, mat_col, mat_row,
                                        e_curs, c_curs, r_curs, e_sorted, i_srow, i_scol);

    for (int hop = 0; hop < 2; ++hop) {
        const float* ent_src = (hop == 0) ? entity_emb : ent_cur;
        const float* usr_src = (hop == 0) ? user_emb : usr_cur;
        int last = (hop == 1);
        edge_agg_k<<<2048, 256, 0, stream>>>(ent_src, wrel, e_starts, e_sorted,
                                             agg, ent_cur, ent_res, last);
        inter_agg_k<<<2048, 256, 0, stream>>>(usr_src, c_starts, i_srow, iint);
        fuse_k<<<1024, 256, 0, stream>>>(agg, iint, g1, g2, ifus,
                                         ent_cur, ent_res, kg_res, int_res);
        user_agg_k<<<2048, 256, 0, stream>>>(ifus, r_starts, i_scol, usr_cur, usr_res);
    }
}

// Round 4
// 1231.917 us; speedup vs baseline: 2.0529x; 1.3856x over previous
//
#include <hip/hip_runtime.h>
#include <math.h>

#define N_USERS    200000
#define N_ITEMS    50000
#define N_ENTITIES 150000
#define N_EDGES    2000000
#define N_INTER    1000000
#define D          64
#define NTOT       (N_EDGES + 2 * N_INTER)

// scan decomposition: chunks of 1250 elements, segments align to chunks
#define CHUNK      1250
#define THR_OWN    5        // 250 active threads * 5 = 1250
#define NBLK_E     120      // 150000 / 1250
#define NBLK_C     40       //  50000 / 1250
#define NBLK_R     160      // 200000 / 1250
#define NBLK_TOT   (NBLK_E + NBLK_C + NBLK_R)   // 320

__device__ __forceinline__ float half_sum32(float v) {
#pragma unroll
    for (int off = 16; off > 0; off >>= 1) v += __shfl_xor(v, off, 64);
    return v;
}

// ---- CSR build: histogram over all three key arrays (grid-stride) ----
__global__ void hist_k(const int* __restrict__ head,
                       const int* __restrict__ mcol,
                       const int* __restrict__ mrow,
                       int* __restrict__ eh, int* __restrict__ ch, int* __restrict__ rh) {
    for (int i = blockIdx.x * blockDim.x + threadIdx.x; i < NTOT;
         i += gridDim.x * blockDim.x) {
        if (i < N_EDGES) atomicAdd(&eh[head[i]], 1);
        else if (i < N_EDGES + N_INTER) atomicAdd(&ch[mcol[i - N_EDGES]], 1);
        else atomicAdd(&rh[mrow[i - N_EDGES - N_INTER]], 1);
    }
}

// ---- scan stage A: per-chunk partial sums (hist arrays are contiguous) ----
__global__ void scanA_k(const int* __restrict__ hist_all,  // e|c|r contiguous
                        int* __restrict__ blk_sums) {
    __shared__ int ss[256];
    int b = blockIdx.x, t = threadIdx.x;
    int base = b * CHUNK;
    int sum = 0;
    if (t < 250) {
        int g = base + t * THR_OWN;
#pragma unroll
        for (int j = 0; j < THR_OWN; ++j) sum += hist_all[g + j];
    }
    ss[t] = sum;
    __syncthreads();
    for (int off = 128; off > 0; off >>= 1) {
        if (t < off) ss[t] += ss[t + off];
        __syncthreads();
    }
    if (t == 0) blk_sums[b] = ss[0];
}

// ---- scan stage B: single small block scans 320 partials, segment-reset ----
__global__ void scanB_k(int* __restrict__ blk_sums, int* __restrict__ blk_off,
                        int* __restrict__ e_starts, int* __restrict__ c_starts,
                        int* __restrict__ r_starts) {
    __shared__ int ss[512];
    int t = threadIdx.x;
    ss[t] = (t < NBLK_TOT) ? blk_sums[t] : 0;
    __syncthreads();
    for (int off = 1; off < 512; off <<= 1) {
        int v = (t >= off) ? ss[t - off] : 0;
        __syncthreads();
        ss[t] += v;   // inclusive scan
        __syncthreads();
    }
    if (t < NBLK_TOT) {
        int excl = (t == 0) ? 0 : ss[t - 1];
        int segstart_excl;
        if (t < NBLK_E) segstart_excl = 0;
        else if (t < NBLK_E + NBLK_C) segstart_excl = ss[NBLK_E - 1];
        else segstart_excl = ss[NBLK_E + NBLK_C - 1];
        blk_off[t] = excl - segstart_excl;
    }
    if (t == 0) {
        e_starts[N_ENTITIES] = N_EDGES;
        c_starts[N_ITEMS]    = N_INTER;
        r_starts[N_USERS]    = N_INTER;
    }
}

// ---- scan stage C: re-scan chunk, write starts + curs ----
__global__ void scanC_k(const int* __restrict__ hist_all,
                        const int* __restrict__ blk_off,
                        int* __restrict__ e_starts, int* __restrict__ c_starts,
                        int* __restrict__ r_starts,
                        int* __restrict__ e_curs, int* __restrict__ c_curs,
                        int* __restrict__ r_curs) {
    __shared__ int ss[256];
    int b = blockIdx.x, t = threadIdx.x;
    int base = b * CHUNK;
    int h[THR_OWN];
    int sum = 0;
    if (t < 250) {
        int g = base + t * THR_OWN;
#pragma unroll
        for (int j = 0; j < THR_OWN; ++j) { h[j] = hist_all[g + j]; sum += h[j]; }
    }
    ss[t] = sum;
    __syncthreads();
    for (int off = 1; off < 256; off <<= 1) {
        int v = (t >= off) ? ss[t - off] : 0;
        __syncthreads();
        ss[t] += v;
        __syncthreads();
    }
    if (t < 250) {
        int run = blk_off[b] + ((t == 0) ? 0 : ss[t - 1]);
        int* s; int* c; int ebase;
        if (b < NBLK_E)               { s = e_starts; c = e_curs; ebase = base; }
        else if (b < NBLK_E + NBLK_C) { s = c_starts; c = c_curs; ebase = base - NBLK_E * CHUNK; }
        else                          { s = r_starts; c = r_curs; ebase = base - (NBLK_E + NBLK_C) * CHUNK; }
        int g = ebase + t * THR_OWN;
#pragma unroll
        for (int j = 0; j < THR_OWN; ++j) { s[g + j] = run; c[g + j] = run; run += h[j]; }
    }
}

// ---- permute: place edges/interactions into segment-sorted arrays ----
__global__ void permute_k(const int* __restrict__ head, const int* __restrict__ tail,
                          const int* __restrict__ type,
                          const int* __restrict__ mcol, const int* __restrict__ mrow,
                          int* __restrict__ ec, int* __restrict__ cc, int* __restrict__ rc,
                          int* __restrict__ e_sorted, int* __restrict__ i_srow,
                          int* __restrict__ i_scol) {
    for (int i = blockIdx.x * blockDim.x + threadIdx.x; i < NTOT;
         i += gridDim.x * blockDim.x) {
        if (i < N_EDGES) {
            int h = head[i];
            int pos = atomicAdd(&ec[h], 1);
            e_sorted[pos] = tail[i] | (type[i] << 18);   // 150K < 2^18, type < 32
        } else if (i < N_EDGES + N_INTER) {
            int j = i - N_EDGES;
            int c = mcol[j];
            int pos = atomicAdd(&cc[c], 1);
            i_srow[pos] = mrow[j];
        } else {
            int j = i - N_EDGES - N_INTER;
            int r = mrow[j];
            int pos = atomicAdd(&rc[r], 1);
            i_scol[pos] = mcol[j];
        }
    }
}

// ---- per-entity aggregation (gather, float2, split-wave). ----
// wave = 2 halves of 32 lanes; per iteration half h processes edges k+h and
// k+2+h; lane hl holds dims (2hl, 2hl+1). ALL __shfl execute with the full
// wave active (uniform loop conditions; tail shfl index clamped, only the
// accumulate is predicated) -- ds_bpermute from a masked lane is undefined.
__global__ void edge_agg_k(const float* __restrict__ ent,
                           const float* __restrict__ wrel,
                           const int* __restrict__ es,
                           const int* __restrict__ e_sorted,
                           float* __restrict__ agg,
                           float* __restrict__ ent_cur,
                           float* __restrict__ ent_res,
                           int last_hop) {
    __shared__ float2 wl2[32 * 32];   // 32 relations x 32 float2
    for (int idx = threadIdx.x; idx < 32 * 32; idx += blockDim.x)
        wl2[idx] = ((const float2*)wrel)[idx];
    __syncthreads();
    const float2* ent2 = (const float2*)ent;
    int lane = threadIdx.x & 63;
    int halfid = lane >> 5, hl = lane & 31;
    int wid = blockIdx.x * (blockDim.x >> 6) + (threadIdx.x >> 6);
    int nw = gridDim.x * (blockDim.x >> 6);
    for (int h = wid; h < N_ENTITIES; h += nw) {
        int beg = es[h], end = es[h + 1];
        float ax0 = 0.f, ay0 = 0.f, ax1 = 0.f, ay1 = 0.f;
        for (int j0 = beg; j0 < end; j0 += 64) {
            int p = (j0 + lane < end) ? e_sorted[j0 + lane] : 0;
            int m = end - j0; if (m > 64) m = 64;
            int k = 0;
            for (; k + 3 < m; k += 4) {      // uniform: k+3 <= m-1, all valid
                int p0 = __shfl(p, k + halfid, 64);
                int p1 = __shfl(p, k + 2 + halfid, 64);
                float2 e0 = ent2[(size_t)(p0 & 0x3FFFF) * 32 + hl];
                float2 w0 = wl2[((p0 >> 18) << 5) + hl];
                float2 e1 = ent2[(size_t)(p1 & 0x3FFFF) * 32 + hl];
                float2 w1 = wl2[((p1 >> 18) << 5) + hl];
                ax0 = fmaf(e0.x, w0.x, ax0); ay0 = fmaf(e0.y, w0.y, ay0);
                ax1 = fmaf(e1.x, w1.x, ax1); ay1 = fmaf(e1.y, w1.y, ay1);
            }
            for (; k < m; k += 2) {          // uniform tail (<=2 iters)
                int i0 = k + halfid;
                int p0 = __shfl(p, i0 & 63, 64);   // full-wave shfl, clamped
                if (i0 < m) {                       // predicate accumulate only
                    float2 e0 = ent2[(size_t)(p0 & 0x3FFFF) * 32 + hl];
                    float2 w0 = wl2[((p0 >> 18) << 5) + hl];
                    ax0 = fmaf(e0.x, w0.x, ax0); ay0 = fmaf(e0.y, w0.y, ay0);
                }
            }
        }
        float ax = ax0 + ax1, ay = ay0 + ay1;
        ax += __shfl_xor(ax, 32, 64);          // combine halves
        ay += __shfl_xor(ay, 32, 64);
        if (h < N_ITEMS) {
            if (halfid == 0) {
                int d = end - beg;
                float inv = 1.0f / (float)(d > 0 ? d : 1);
                float2 o; o.x = ax * inv; o.y = ay * inv;
                ((float2*)agg)[(size_t)h * 32 + hl] = o;
            }
        } else {
            // l2norm(mean) == l2norm(sum): scale-invariant
            float s = half_sum32(ax * ax + ay * ay);
            float inv = 1.0f / fmaxf(sqrtf(s), 1e-12f);
            float2 vn; vn.x = ax * inv; vn.y = ay * inv;
            size_t off = (size_t)h * 32 + hl;
            if (halfid == 0) {
                if (!last_hop) ((float2*)ent_cur)[off] = vn;
            } else {
                float2 r = ((float2*)ent_res)[off];
                r.x += vn.x; r.y += vn.y;
                ((float2*)ent_res)[off] = r;
            }
        }
    }
}

// ---- per-item interaction mean (gather, float2, split-wave, uniform) ----
__global__ void inter_agg_k(const float* __restrict__ usr,
                            const int* __restrict__ cs,
                            const int* __restrict__ i_srow,
                            float* __restrict__ iint) {
    const float2* usr2 = (const float2*)usr;
    int lane = threadIdx.x & 63;
    int halfid = lane >> 5, hl = lane & 31;
    int wid = blockIdx.x * (blockDim.x >> 6) + (threadIdx.x >> 6);
    int nw = gridDim.x * (blockDim.x >> 6);
    for (int c = wid; c < N_ITEMS; c += nw) {
        int beg = cs[c], end = cs[c + 1];
        float ax0 = 0.f, ay0 = 0.f, ax1 = 0.f, ay1 = 0.f;
        for (int j0 = beg; j0 < end; j0 += 64) {
            int p = (j0 + lane < end) ? i_srow[j0 + lane] : 0;
            int m = end - j0; if (m > 64) m = 64;
            int k = 0;
            for (; k + 3 < m; k += 4) {
                int p0 = __shfl(p, k + halfid, 64);
                int p1 = __shfl(p, k + 2 + halfid, 64);
                float2 u0 = usr2[(size_t)p0 * 32 + hl];
                float2 u1 = usr2[(size_t)p1 * 32 + hl];
                ax0 += u0.x; ay0 += u0.y; ax1 += u1.x; ay1 += u1.y;
            }
            for (; k < m; k += 2) {
                int i0 = k + halfid;
                int p0 = __shfl(p, i0 & 63, 64);
                if (i0 < m) {
                    float2 u0 = usr2[(size_t)p0 * 32 + hl];
                    ax0 += u0.x; ay0 += u0.y;
                }
            }
        }
        float ax = ax0 + ax1, ay = ay0 + ay1;
        ax += __shfl_xor(ax, 32, 64);
        ay += __shfl_xor(ay, 32, 64);
        if (halfid == 0) {
            int d = end - beg;
            float inv = 1.0f / (float)(d > 0 ? d : 1);
            float2 o; o.x = ax * inv; o.y = ay * inv;
            ((float2*)iint)[(size_t)c * 32 + hl] = o;
        }
    }
}

// ---- gate + fusion + norms + residuals. agg/iint are already means. ----
// ifus may alias iint (per-thread read-before-write at same address).
__global__ void fuse_k(const float* __restrict__ agg,
                       const float* __restrict__ iint,
                       const float* __restrict__ g1,
                       const float* __restrict__ g2,
                       float* __restrict__ ifus,
                       float* __restrict__ ent_cur,
                       float* __restrict__ ent_res,
                       float* __restrict__ kg_res,
                       float* __restrict__ int_res) {
    __shared__ float g1s[64 * 65];
    __shared__ float g2s[64 * 65];
    for (int idx = threadIdx.x; idx < 64 * 64; idx += blockDim.x) {
        int r = idx >> 6, c = idx & 63;
        g1s[r * 65 + c] = g1[idx];
        g2s[r * 65 + c] = g2[idx];
    }
    __syncthreads();
    int lane = threadIdx.x & 63;
    int wid = blockIdx.x * (blockDim.x >> 6) + (threadIdx.x >> 6);
    int nw = gridDim.x * (blockDim.x >> 6);
    int jb = lane * 65;
    for (int i = wid; i < N_ITEMS; i += nw) {
        float kg = agg[(size_t)i * D + lane];
        float ii = iint[(size_t)i * D + lane];
        float y = 0.f;
#pragma unroll
        for (int k = 0; k < 64; ++k) {
            y = fmaf(__shfl(kg, k, 64), g1s[jb + k], y);
            y = fmaf(__shfl(ii, k, 64), g2s[jb + k], y);
        }
        float gi = 1.0f / (1.0f + __expf(-y));
        float fus = gi * kg + (1.0f - gi) * ii;
        ifus[(size_t)i * D + lane] = fus;
        float vf = fus * fus, vk = kg * kg, vi = ii * ii;
#pragma unroll
        for (int off = 32; off > 0; off >>= 1) {
            vf += __shfl_xor(vf, off, 64);
            vk += __shfl_xor(vk, off, 64);
            vi += __shfl_xor(vi, off, 64);
        }
        float fn = fus / fmaxf(sqrtf(vf), 1e-12f);
        ent_cur[(size_t)i * D + lane] = fn;
        ent_res[(size_t)i * D + lane] += fn;
        kg_res[(size_t)i * D + lane] += kg / fmaxf(sqrtf(vk), 1e-12f);
        int_res[(size_t)i * D + lane] += ii / fmaxf(sqrtf(vi), 1e-12f);
    }
}

// ---- per-user segment sum of item_fusion + l2 norm (float2, uniform) ----
__global__ void user_agg_k(const float* __restrict__ ifus,
                           const int* __restrict__ rs,
                           const int* __restrict__ i_scol,
                           float* __restrict__ usr_cur,
                           float* __restrict__ usr_res) {
    const float2* if2 = (const float2*)ifus;
    int lane = threadIdx.x & 63;
    int halfid = lane >> 5, hl = lane & 31;
    int wid = blockIdx.x * (blockDim.x >> 6) + (threadIdx.x >> 6);
    int nw = gridDim.x * (blockDim.x >> 6);
    for (int u = wid; u < N_USERS; u += nw) {
        int beg = rs[u], end = rs[u + 1];
        float ax0 = 0.f, ay0 = 0.f, ax1 = 0.f, ay1 = 0.f;
        for (int j0 = beg; j0 < end; j0 += 64) {
            int p = (j0 + lane < end) ? i_scol[j0 + lane] : 0;
            int m = end - j0; if (m > 64) m = 64;
            int k = 0;
            for (; k + 3 < m; k += 4) {
                int p0 = __shfl(p, k + halfid, 64);
                int p1 = __shfl(p, k + 2 + halfid, 64);
                float2 u0 = if2[(size_t)p0 * 32 + hl];
                float2 u1 = if2[(size_t)p1 * 32 + hl];
                ax0 += u0.x; ay0 += u0.y; ax1 += u1.x; ay1 += u1.y;
            }
            for (; k < m; k += 2) {
                int i0 = k + halfid;
                int p0 = __shfl(p, i0 & 63, 64);
                if (i0 < m) {
                    float2 u0 = if2[(size_t)p0 * 32 + hl];
                    ax0 += u0.x; ay0 += u0.y;
                }
            }
        }
        float ax = ax0 + ax1, ay = ay0 + ay1;
        ax += __shfl_xor(ax, 32, 64);
        ay += __shfl_xor(ay, 32, 64);
        float s = half_sum32(ax * ax + ay * ay);
        float inv = 1.0f / fmaxf(sqrtf(s), 1e-12f);
        float2 vn; vn.x = ax * inv; vn.y = ay * inv;
        size_t off = (size_t)u * 32 + hl;
        if (halfid == 0) {
            ((float2*)usr_cur)[off] = vn;
        } else {
            float2 r = ((float2*)usr_res)[off];
            r.x += vn.x; r.y += vn.y;
            ((float2*)usr_res)[off] = r;
        }
    }
}

extern "C" void kernel_launch(void* const* d_in, const int* in_sizes, int n_in,
                              void* d_out, int out_size, void* d_ws, size_t ws_size,
                              hipStream_t stream) {
    const float* user_emb   = (const float*)d_in[0];
    const float* entity_emb = (const float*)d_in[1];
    const float* wrel       = (const float*)d_in[2];
    const float* g1         = (const float*)d_in[3];
    const float* g2         = (const float*)d_in[4];
    const int*   edge_head  = (const int*)d_in[5];
    const int*   edge_tail  = (const int*)d_in[6];
    const int*   edge_type  = (const int*)d_in[7];
    const int*   mat_row    = (const int*)d_in[8];
    const int*   mat_col    = (const int*)d_in[9];

    const size_t ENT_SZ = (size_t)N_ENTITIES * D;  //  9.6M
    const size_t USR_SZ = (size_t)N_USERS * D;     // 12.8M
    const size_t ITM_SZ = (size_t)N_ITEMS * D;     //  3.2M

    float* out     = (float*)d_out;
    float* ent_res = out;
    float* usr_res = out + ENT_SZ;
    float* kg_res  = out + ENT_SZ + USR_SZ;
    float* int_res = out + ENT_SZ + USR_SZ + ITM_SZ;

    // workspace layout
    float* ws      = (float*)d_ws;
    float* ent_cur = ws;                        // 9.6M f
    float* usr_cur = ent_cur + ENT_SZ;          // 12.8M f
    float* agg     = usr_cur + USR_SZ;          // 3.2M f (item kg means)
    float* iint    = agg + ITM_SZ;              // 3.2M f (aliases ifus)
    float* ifus    = iint;                      // alias: read-before-write per thread
    int*   e_hist  = (int*)(iint + ITM_SZ);     // 150000  } contiguous:
    int*   c_hist  = e_hist + N_ENTITIES;       //  50000  } one memset +
    int*   r_hist  = c_hist + N_ITEMS;          // 200000  } one scan input
    int*   e_starts = r_hist + N_USERS;         // 150001
    int*   c_starts = e_starts + N_ENTITIES + 1;//  50001
    int*   r_starts = c_starts + N_ITEMS + 1;   // 200001
    int*   e_curs   = r_starts + N_USERS + 1;   // 150000
    int*   c_curs   = e_curs + N_ENTITIES;      //  50000
    int*   r_curs   = c_curs + N_ITEMS;         // 200000
    int*   e_sorted = r_curs + N_USERS;         // 2,000,000 (tail | type<<18)
    int*   i_srow   = e_sorted + N_EDGES;       // 1,000,000
    int*   i_scol   = i_srow + N_INTER;         // 1,000,000
    int*   blk_sums = i_scol + N_INTER;         // 320
    int*   blk_off  = blk_sums + NBLK_TOT;      // 320

    // init outputs + histograms
    hipMemcpyAsync(ent_res, entity_emb, ENT_SZ * sizeof(float), hipMemcpyDeviceToDevice, stream);
    hipMemcpyAsync(usr_res, user_emb,   USR_SZ * sizeof(float), hipMemcpyDeviceToDevice, stream);
    hipMemsetAsync(kg_res, 0, 2 * ITM_SZ * sizeof(float), stream);
    hipMemsetAsync(e_hist, 0, (N_ENTITIES + N_ITEMS + N_USERS) * sizeof(int), stream);

    // CSR build (hop-invariant)
    hist_k<<<4096, 256, 0, stream>>>(edge_head, mat_col, mat_row, e_hist, c_hist, r_hist);
    scanA_k<<<NBLK_TOT, 256, 0, stream>>>(e_hist, blk_sums);
    scanB_k<<<1, 512, 0, stream>>>(blk_sums, blk_off, e_starts, c_starts, r_starts);
    scanC_k<<<NBLK_TOT, 256, 0, stream>>>(e_hist, blk_off,
                                          e_starts, c_starts, r_starts,
                                          e_curs, c_curs, r_curs);
    permute_k<<<4096, 256, 0, stream>>>(edge_head, edge_tail, edge_type, mat_col, mat_row,
                                        e_curs, c_curs, r_curs, e_sorted, i_srow, i_scol);

    for (int hop = 0; hop < 2; ++hop) {
        const float* ent_src = (hop == 0) ? entity_emb : ent_cur;
        const float* usr_src = (hop == 0) ? user_emb : usr_cur;
        int last = (hop == 1);
        edge_agg_k<<<2048, 256, 0, stream>>>(ent_src, wrel, e_starts, e_sorted,
                                             agg, ent_cur, ent_res, last);
        inter_agg_k<<<2048, 256, 0, stream>>>(usr_src, c_starts, i_srow, iint);
        fuse_k<<<1024, 256, 0, stream>>>(agg, iint, g1, g2, ifus,
                                         ent_cur, ent_res, kg_res, int_res);
        user_agg_k<<<2048, 256, 0, stream>>>(ifus, r_starts, i_scol, usr_cur, usr_res);
    }
}

// Round 5
// 1100.775 us; speedup vs baseline: 2.2975x; 1.1191x over previous
//
#include <hip/hip_runtime.h>
#include <math.h>

#define N_USERS    200000
#define N_ITEMS    50000
#define N_ENTITIES 150000
#define N_EDGES    2000000
#define N_INTER    1000000
#define D          64
#define NTOT       (N_EDGES + 2 * N_INTER)

// scan decomposition: chunks of 1250 elements, segments align to chunks
#define CHUNK      1250
#define THR_OWN    5        // 250 active threads * 5 = 1250
#define NBLK_E     120      // 150000 / 1250
#define NBLK_C     40       //  50000 / 1250
#define NBLK_R     160      // 200000 / 1250
#define NBLK_TOT   (NBLK_E + NBLK_C + NBLK_R)   // 320

__device__ __forceinline__ float half_sum32(float v) {
#pragma unroll
    for (int off = 16; off > 0; off >>= 1) v += __shfl_xor(v, off, 64);
    return v;
}

// ---- CSR build: histogram over all three key arrays (grid-stride) ----
__global__ void hist_k(const int* __restrict__ head,
                       const int* __restrict__ mcol,
                       const int* __restrict__ mrow,
                       int* __restrict__ eh, int* __restrict__ ch, int* __restrict__ rh) {
    for (int i = blockIdx.x * blockDim.x + threadIdx.x; i < NTOT;
         i += gridDim.x * blockDim.x) {
        if (i < N_EDGES) atomicAdd(&eh[head[i]], 1);
        else if (i < N_EDGES + N_INTER) atomicAdd(&ch[mcol[i - N_EDGES]], 1);
        else atomicAdd(&rh[mrow[i - N_EDGES - N_INTER]], 1);
    }
}

// ---- scan stage A: per-chunk partial sums (hist arrays are contiguous) ----
__global__ void scanA_k(const int* __restrict__ hist_all,  // e|c|r contiguous
                        int* __restrict__ blk_sums) {
    __shared__ int ss[256];
    int b = blockIdx.x, t = threadIdx.x;
    int base = b * CHUNK;
    int sum = 0;
    if (t < 250) {
        int g = base + t * THR_OWN;
#pragma unroll
        for (int j = 0; j < THR_OWN; ++j) sum += hist_all[g + j];
    }
    ss[t] = sum;
    __syncthreads();
    for (int off = 128; off > 0; off >>= 1) {
        if (t < off) ss[t] += ss[t + off];
        __syncthreads();
    }
    if (t == 0) blk_sums[b] = ss[0];
}

// ---- scan stage B: single small block scans 320 partials, segment-reset ----
__global__ void scanB_k(int* __restrict__ blk_sums, int* __restrict__ blk_off,
                        int* __restrict__ e_starts, int* __restrict__ c_starts,
                        int* __restrict__ r_starts) {
    __shared__ int ss[512];
    int t = threadIdx.x;
    ss[t] = (t < NBLK_TOT) ? blk_sums[t] : 0;
    __syncthreads();
    for (int off = 1; off < 512; off <<= 1) {
        int v = (t >= off) ? ss[t - off] : 0;
        __syncthreads();
        ss[t] += v;   // inclusive scan
        __syncthreads();
    }
    if (t < NBLK_TOT) {
        int excl = (t == 0) ? 0 : ss[t - 1];
        int segstart_excl;
        if (t < NBLK_E) segstart_excl = 0;
        else if (t < NBLK_E + NBLK_C) segstart_excl = ss[NBLK_E - 1];
        else segstart_excl = ss[NBLK_E + NBLK_C - 1];
        blk_off[t] = excl - segstart_excl;
    }
    if (t == 0) {
        e_starts[N_ENTITIES] = N_EDGES;
        c_starts[N_ITEMS]    = N_INTER;
        r_starts[N_USERS]    = N_INTER;
    }
}

// ---- scan stage C: re-scan chunk, write starts + curs ----
__global__ void scanC_k(const int* __restrict__ hist_all,
                        const int* __restrict__ blk_off,
                        int* __restrict__ e_starts, int* __restrict__ c_starts,
                        int* __restrict__ r_starts,
                        int* __restrict__ e_curs, int* __restrict__ c_curs,
                        int* __restrict__ r_curs) {
    __shared__ int ss[256];
    int b = blockIdx.x, t = threadIdx.x;
    int base = b * CHUNK;
    int h[THR_OWN];
    int sum = 0;
    if (t < 250) {
        int g = base + t * THR_OWN;
#pragma unroll
        for (int j = 0; j < THR_OWN; ++j) { h[j] = hist_all[g + j]; sum += h[j]; }
    }
    ss[t] = sum;
    __syncthreads();
    for (int off = 1; off < 256; off <<= 1) {
        int v = (t >= off) ? ss[t - off] : 0;
        __syncthreads();
        ss[t] += v;
        __syncthreads();
    }
    if (t < 250) {
        int run = blk_off[b] + ((t == 0) ? 0 : ss[t - 1]);
        int* s; int* c; int ebase;
        if (b < NBLK_E)               { s = e_starts; c = e_curs; ebase = base; }
        else if (b < NBLK_E + NBLK_C) { s = c_starts; c = c_curs; ebase = base - NBLK_E * CHUNK; }
        else                          { s = r_starts; c = r_curs; ebase = base - (NBLK_E + NBLK_C) * CHUNK; }
        int g = ebase + t * THR_OWN;
#pragma unroll
        for (int j = 0; j < THR_OWN; ++j) { s[g + j] = run; c[g + j] = run; run += h[j]; }
    }
}

// ---- permute, XCD-partitioned by key range to kill write amplification ----
// Block's xcd id (blockIdx&7, round-robin dispatch heuristic) owns heads in
// [xcd*18750, (xcd+1)*18750). Each slot-group grid-strides the WHOLE edge
// list, processes only in-range keys -> segment-frontier lines per XCD =
// 18750*64B = 1.2 MB, fits 4 MB L2 -> stores coalesce to full lines.
// Correctness does not depend on the blockIdx->XCD mapping.
__global__ void permute_e_k(const int* __restrict__ head, const int* __restrict__ tail,
                            const int* __restrict__ type,
                            int* __restrict__ ec, int* __restrict__ e_sorted) {
    int xcd = blockIdx.x & 7;
    int slot = blockIdx.x >> 3;
    int nslot = gridDim.x >> 3;
    int lo = xcd * (N_ENTITIES / 8);
    int hi = lo + (N_ENTITIES / 8);
    for (int i = slot * blockDim.x + threadIdx.x; i < N_EDGES;
         i += nslot * blockDim.x) {
        int h = __builtin_nontemporal_load(&head[i]);
        if (h >= lo && h < hi) {
            int pos = atomicAdd(&ec[h], 1);
            int t = __builtin_nontemporal_load(&tail[i]);
            int r = __builtin_nontemporal_load(&type[i]);
            e_sorted[pos] = t | (r << 18);   // 150K < 2^18, type < 32
        }
    }
}

__global__ void permute_i_k(const int* __restrict__ mcol, const int* __restrict__ mrow,
                            int* __restrict__ cc, int* __restrict__ rc,
                            int* __restrict__ i_srow, int* __restrict__ i_scol) {
    int xcd = blockIdx.x & 7;
    int slot = blockIdx.x >> 3;
    int nslot = gridDim.x >> 3;
    int clo = xcd * (N_ITEMS / 8), chi = clo + (N_ITEMS / 8);
    int rlo = xcd * (N_USERS / 8), rhi = rlo + (N_USERS / 8);
    for (int i = slot * blockDim.x + threadIdx.x; i < N_INTER;
         i += nslot * blockDim.x) {
        int c = __builtin_nontemporal_load(&mcol[i]);
        int r = __builtin_nontemporal_load(&mrow[i]);
        if (c >= clo && c < chi) {
            int pos = atomicAdd(&cc[c], 1);
            i_srow[pos] = r;
        }
        if (r >= rlo && r < rhi) {
            int pos = atomicAdd(&rc[r], 1);
            i_scol[pos] = c;
        }
    }
}

// ---- per-entity aggregation (gather, float2, split-wave). ----
// wave = 2 halves of 32 lanes; per iteration half h processes edges k+h and
// k+2+h; lane hl holds dims (2hl, 2hl+1). ALL __shfl execute with the full
// wave active (uniform loop conditions; tail shfl index clamped, only the
// accumulate is predicated) -- ds_bpermute from a masked lane is undefined.
__global__ void edge_agg_k(const float* __restrict__ ent,
                           const float* __restrict__ wrel,
                           const int* __restrict__ es,
                           const int* __restrict__ e_sorted,
                           float* __restrict__ agg,
                           float* __restrict__ ent_cur,
                           float* __restrict__ ent_res,
                           int last_hop) {
    __shared__ float2 wl2[32 * 32];   // 32 relations x 32 float2
    for (int idx = threadIdx.x; idx < 32 * 32; idx += blockDim.x)
        wl2[idx] = ((const float2*)wrel)[idx];
    __syncthreads();
    const float2* ent2 = (const float2*)ent;
    int lane = threadIdx.x & 63;
    int halfid = lane >> 5, hl = lane & 31;
    int wid = blockIdx.x * (blockDim.x >> 6) + (threadIdx.x >> 6);
    int nw = gridDim.x * (blockDim.x >> 6);
    for (int h = wid; h < N_ENTITIES; h += nw) {
        int beg = es[h], end = es[h + 1];
        float ax0 = 0.f, ay0 = 0.f, ax1 = 0.f, ay1 = 0.f;
        for (int j0 = beg; j0 < end; j0 += 64) {
            int p = (j0 + lane < end) ? e_sorted[j0 + lane] : 0;
            int m = end - j0; if (m > 64) m = 64;
            int k = 0;
            for (; k + 3 < m; k += 4) {      // uniform: k+3 <= m-1, all valid
                int p0 = __shfl(p, k + halfid, 64);
                int p1 = __shfl(p, k + 2 + halfid, 64);
                float2 e0 = ent2[(size_t)(p0 & 0x3FFFF) * 32 + hl];
                float2 w0 = wl2[((p0 >> 18) << 5) + hl];
                float2 e1 = ent2[(size_t)(p1 & 0x3FFFF) * 32 + hl];
                float2 w1 = wl2[((p1 >> 18) << 5) + hl];
                ax0 = fmaf(e0.x, w0.x, ax0); ay0 = fmaf(e0.y, w0.y, ay0);
                ax1 = fmaf(e1.x, w1.x, ax1); ay1 = fmaf(e1.y, w1.y, ay1);
            }
            for (; k < m; k += 2) {          // uniform tail (<=2 iters)
                int i0 = k + halfid;
                int p0 = __shfl(p, i0 & 63, 64);   // full-wave shfl, clamped
                if (i0 < m) {                       // predicate accumulate only
                    float2 e0 = ent2[(size_t)(p0 & 0x3FFFF) * 32 + hl];
                    float2 w0 = wl2[((p0 >> 18) << 5) + hl];
                    ax0 = fmaf(e0.x, w0.x, ax0); ay0 = fmaf(e0.y, w0.y, ay0);
                }
            }
        }
        float ax = ax0 + ax1, ay = ay0 + ay1;
        ax += __shfl_xor(ax, 32, 64);          // combine halves
        ay += __shfl_xor(ay, 32, 64);
        if (h < N_ITEMS) {
            if (halfid == 0) {
                int d = end - beg;
                float inv = 1.0f / (float)(d > 0 ? d : 1);
                float2 o; o.x = ax * inv; o.y = ay * inv;
                ((float2*)agg)[(size_t)h * 32 + hl] = o;
            }
        } else {
            // l2norm(mean) == l2norm(sum): scale-invariant
            float s = half_sum32(ax * ax + ay * ay);
            float inv = 1.0f / fmaxf(sqrtf(s), 1e-12f);
            float2 vn; vn.x = ax * inv; vn.y = ay * inv;
            size_t off = (size_t)h * 32 + hl;
            if (halfid == 0) {
                if (!last_hop) ((float2*)ent_cur)[off] = vn;
            } else {
                float2 r = ((float2*)ent_res)[off];
                r.x += vn.x; r.y += vn.y;
                ((float2*)ent_res)[off] = r;
            }
        }
    }
}

// ---- per-item interaction mean (gather, float2, split-wave, uniform) ----
__global__ void inter_agg_k(const float* __restrict__ usr,
                            const int* __restrict__ cs,
                            const int* __restrict__ i_srow,
                            float* __restrict__ iint) {
    const float2* usr2 = (const float2*)usr;
    int lane = threadIdx.x & 63;
    int halfid = lane >> 5, hl = lane & 31;
    int wid = blockIdx.x * (blockDim.x >> 6) + (threadIdx.x >> 6);
    int nw = gridDim.x * (blockDim.x >> 6);
    for (int c = wid; c < N_ITEMS; c += nw) {
        int beg = cs[c], end = cs[c + 1];
        float ax0 = 0.f, ay0 = 0.f, ax1 = 0.f, ay1 = 0.f;
        for (int j0 = beg; j0 < end; j0 += 64) {
            int p = (j0 + lane < end) ? i_srow[j0 + lane] : 0;
            int m = end - j0; if (m > 64) m = 64;
            int k = 0;
            for (; k + 3 < m; k += 4) {
                int p0 = __shfl(p, k + halfid, 64);
                int p1 = __shfl(p, k + 2 + halfid, 64);
                float2 u0 = usr2[(size_t)p0 * 32 + hl];
                float2 u1 = usr2[(size_t)p1 * 32 + hl];
                ax0 += u0.x; ay0 += u0.y; ax1 += u1.x; ay1 += u1.y;
            }
            for (; k < m; k += 2) {
                int i0 = k + halfid;
                int p0 = __shfl(p, i0 & 63, 64);
                if (i0 < m) {
                    float2 u0 = usr2[(size_t)p0 * 32 + hl];
                    ax0 += u0.x; ay0 += u0.y;
                }
            }
        }
        float ax = ax0 + ax1, ay = ay0 + ay1;
        ax += __shfl_xor(ax, 32, 64);
        ay += __shfl_xor(ay, 32, 64);
        if (halfid == 0) {
            int d = end - beg;
            float inv = 1.0f / (float)(d > 0 ? d : 1);
            float2 o; o.x = ax * inv; o.y = ay * inv;
            ((float2*)iint)[(size_t)c * 32 + hl] = o;
        }
    }
}

// ---- gate + fusion + norms + residuals. agg/iint are already means. ----
// ifus may alias iint (per-thread read-before-write at same address).
__global__ void fuse_k(const float* __restrict__ agg,
                       const float* __restrict__ iint,
                       const float* __restrict__ g1,
                       const float* __restrict__ g2,
                       float* __restrict__ ifus,
                       float* __restrict__ ent_cur,
                       float* __restrict__ ent_res,
                       float* __restrict__ kg_res,
                       float* __restrict__ int_res) {
    __shared__ float g1s[64 * 65];
    __shared__ float g2s[64 * 65];
    for (int idx = threadIdx.x; idx < 64 * 64; idx += blockDim.x) {
        int r = idx >> 6, c = idx & 63;
        g1s[r * 65 + c] = g1[idx];
        g2s[r * 65 + c] = g2[idx];
    }
    __syncthreads();
    int lane = threadIdx.x & 63;
    int wid = blockIdx.x * (blockDim.x >> 6) + (threadIdx.x >> 6);
    int nw = gridDim.x * (blockDim.x >> 6);
    int jb = lane * 65;
    for (int i = wid; i < N_ITEMS; i += nw) {
        float kg = agg[(size_t)i * D + lane];
        float ii = iint[(size_t)i * D + lane];
        float y = 0.f;
#pragma unroll
        for (int k = 0; k < 64; ++k) {
            y = fmaf(__shfl(kg, k, 64), g1s[jb + k], y);
            y = fmaf(__shfl(ii, k, 64), g2s[jb + k], y);
        }
        float gi = 1.0f / (1.0f + __expf(-y));
        float fus = gi * kg + (1.0f - gi) * ii;
        ifus[(size_t)i * D + lane] = fus;
        float vf = fus * fus, vk = kg * kg, vi = ii * ii;
#pragma unroll
        for (int off = 32; off > 0; off >>= 1) {
            vf += __shfl_xor(vf, off, 64);
            vk += __shfl_xor(vk, off, 64);
            vi += __shfl_xor(vi, off, 64);
        }
        float fn = fus / fmaxf(sqrtf(vf), 1e-12f);
        ent_cur[(size_t)i * D + lane] = fn;
        ent_res[(size_t)i * D + lane] += fn;
        kg_res[(size_t)i * D + lane] += kg / fmaxf(sqrtf(vk), 1e-12f);
        int_res[(size_t)i * D + lane] += ii / fmaxf(sqrtf(vi), 1e-12f);
    }
}

// ---- per-user segment sum of item_fusion + l2 norm (float2, uniform) ----
__global__ void user_agg_k(const float* __restrict__ ifus,
                           const int* __restrict__ rs,
                           const int* __restrict__ i_scol,
                           float* __restrict__ usr_cur,
                           float* __restrict__ usr_res) {
    const float2* if2 = (const float2*)ifus;
    int lane = threadIdx.x & 63;
    int halfid = lane >> 5, hl = lane & 31;
    int wid = blockIdx.x * (blockDim.x >> 6) + (threadIdx.x >> 6);
    int nw = gridDim.x * (blockDim.x >> 6);
    for (int u = wid; u < N_USERS; u += nw) {
        int beg = rs[u], end = rs[u + 1];
        float ax0 = 0.f, ay0 = 0.f, ax1 = 0.f, ay1 = 0.f;
        for (int j0 = beg; j0 < end; j0 += 64) {
            int p = (j0 + lane < end) ? i_scol[j0 + lane] : 0;
            int m = end - j0; if (m > 64) m = 64;
            int k = 0;
            for (; k + 3 < m; k += 4) {
                int p0 = __shfl(p, k + halfid, 64);
                int p1 = __shfl(p, k + 2 + halfid, 64);
                float2 u0 = if2[(size_t)p0 * 32 + hl];
                float2 u1 = if2[(size_t)p1 * 32 + hl];
                ax0 += u0.x; ay0 += u0.y; ax1 += u1.x; ay1 += u1.y;
            }
            for (; k < m; k += 2) {
                int i0 = k + halfid;
                int p0 = __shfl(p, i0 & 63, 64);
                if (i0 < m) {
                    float2 u0 = if2[(size_t)p0 * 32 + hl];
                    ax0 += u0.x; ay0 += u0.y;
                }
            }
        }
        float ax = ax0 + ax1, ay = ay0 + ay1;
        ax += __shfl_xor(ax, 32, 64);
        ay += __shfl_xor(ay, 32, 64);
        float s = half_sum32(ax * ax + ay * ay);
        float inv = 1.0f / fmaxf(sqrtf(s), 1e-12f);
        float2 vn; vn.x = ax * inv; vn.y = ay * inv;
        size_t off = (size_t)u * 32 + hl;
        if (halfid == 0) {
            ((float2*)usr_cur)[off] = vn;
        } else {
            float2 r = ((float2*)usr_res)[off];
            r.x += vn.x; r.y += vn.y;
            ((float2*)usr_res)[off] = r;
        }
    }
}

extern "C" void kernel_launch(void* const* d_in, const int* in_sizes, int n_in,
                              void* d_out, int out_size, void* d_ws, size_t ws_size,
                              hipStream_t stream) {
    const float* user_emb   = (const float*)d_in[0];
    const float* entity_emb = (const float*)d_in[1];
    const float* wrel       = (const float*)d_in[2];
    const float* g1         = (const float*)d_in[3];
    const float* g2         = (const float*)d_in[4];
    const int*   edge_head  = (const int*)d_in[5];
    const int*   edge_tail  = (const int*)d_in[6];
    const int*   edge_type  = (const int*)d_in[7];
    const int*   mat_row    = (const int*)d_in[8];
    const int*   mat_col    = (const int*)d_in[9];

    const size_t ENT_SZ = (size_t)N_ENTITIES * D;  //  9.6M
    const size_t USR_SZ = (size_t)N_USERS * D;     // 12.8M
    const size_t ITM_SZ = (size_t)N_ITEMS * D;     //  3.2M

    float* out     = (float*)d_out;
    float* ent_res = out;
    float* usr_res = out + ENT_SZ;
    float* kg_res  = out + ENT_SZ + USR_SZ;
    float* int_res = out + ENT_SZ + USR_SZ + ITM_SZ;

    // workspace layout
    float* ws      = (float*)d_ws;
    float* ent_cur = ws;                        // 9.6M f
    float* usr_cur = ent_cur + ENT_SZ;          // 12.8M f
    float* agg     = usr_cur + USR_SZ;          // 3.2M f (item kg means)
    float* iint    = agg + ITM_SZ;              // 3.2M f (aliases ifus)
    float* ifus    = iint;                      // alias: read-before-write per thread
    int*   e_hist  = (int*)(iint + ITM_SZ);     // 150000  } contiguous:
    int*   c_hist  = e_hist + N_ENTITIES;       //  50000  } one memset +
    int*   r_hist  = c_hist + N_ITEMS;          // 200000  } one scan input
    int*   e_starts = r_hist + N_USERS;         // 150001
    int*   c_starts = e_starts + N_ENTITIES + 1;//  50001
    int*   r_starts = c_starts + N_ITEMS + 1;   // 200001
    int*   e_curs   = r_starts + N_USERS + 1;   // 150000
    int*   c_curs   = e_curs + N_ENTITIES;      //  50000
    int*   r_curs   = c_curs + N_ITEMS;         // 200000
    int*   e_sorted = r_curs + N_USERS;         // 2,000,000 (tail | type<<18)
    int*   i_srow   = e_sorted + N_EDGES;       // 1,000,000
    int*   i_scol   = i_srow + N_INTER;         // 1,000,000
    int*   blk_sums = i_scol + N_INTER;         // 320
    int*   blk_off  = blk_sums + NBLK_TOT;      // 320

    // init outputs + histograms
    hipMemcpyAsync(ent_res, entity_emb, ENT_SZ * sizeof(float), hipMemcpyDeviceToDevice, stream);
    hipMemcpyAsync(usr_res, user_emb,   USR_SZ * sizeof(float), hipMemcpyDeviceToDevice, stream);
    hipMemsetAsync(kg_res, 0, 2 * ITM_SZ * sizeof(float), stream);
    hipMemsetAsync(e_hist, 0, (N_ENTITIES + N_ITEMS + N_USERS) * sizeof(int), stream);

    // CSR build (hop-invariant)
    hist_k<<<4096, 256, 0, stream>>>(edge_head, mat_col, mat_row, e_hist, c_hist, r_hist);
    scanA_k<<<NBLK_TOT, 256, 0, stream>>>(e_hist, blk_sums);
    scanB_k<<<1, 512, 0, stream>>>(blk_sums, blk_off, e_starts, c_starts, r_starts);
    scanC_k<<<NBLK_TOT, 256, 0, stream>>>(e_hist, blk_off,
                                          e_starts, c_starts, r_starts,
                                          e_curs, c_curs, r_curs);
    permute_e_k<<<4096, 256, 0, stream>>>(edge_head, edge_tail, edge_type,
                                          e_curs, e_sorted);
    permute_i_k<<<4096, 256, 0, stream>>>(mat_col, mat_row,
                                          c_curs, r_curs, i_srow, i_scol);

    for (int hop = 0; hop < 2; ++hop) {
        const float* ent_src = (hop == 0) ? entity_emb : ent_cur;
        const float* usr_src = (hop == 0) ? user_emb : usr_cur;
        int last = (hop == 1);
        edge_agg_k<<<2048, 256, 0, stream>>>(ent_src, wrel, e_starts, e_sorted,
                                             agg, ent_cur, ent_res, last);
        inter_agg_k<<<2048, 256, 0, stream>>>(usr_src, c_starts, i_srow, iint);
        fuse_k<<<1024, 256, 0, stream>>>(agg, iint, g1, g2, ifus,
                                         ent_cur, ent_res, kg_res, int_res);
        user_agg_k<<<2048, 256, 0, stream>>>(ifus, r_starts, i_scol, usr_cur, usr_res);
    }
}

// Round 6
// 844.841 us; speedup vs baseline: 2.9934x; 1.3029x over previous
//
#include <hip/hip_runtime.h>
#include <math.h>

#define N_USERS    200000
#define N_ITEMS    50000
#define N_ENTITIES 150000
#define N_EDGES    2000000
#define N_INTER    1000000
#define D          64
#define NTOT       (N_EDGES + 2 * N_INTER)

// scan decomposition: chunks of 1250 elements, segments align to chunks
#define CHUNK      1250
#define THR_OWN    5        // 250 active threads * 5 = 1250
#define NBLK_E     120      // 150000 / 1250
#define NBLK_C     40       //  50000 / 1250
#define NBLK_R     160      // 200000 / 1250
#define NBLK_TOT   (NBLK_E + NBLK_C + NBLK_R)   // 320

// fuse GEMM tiling
#define FT    64            // items per tile
#define FPAD  132           // LDS row stride in floats (128 + 4)
#define NTILE ((N_ITEMS + FT - 1) / FT)   // 782

__device__ __forceinline__ float half_sum32(float v) {
#pragma unroll
    for (int off = 16; off > 0; off >>= 1) v += __shfl_xor(v, off, 64);
    return v;
}

// ---- CSR build: histogram over all three key arrays (grid-stride) ----
__global__ void hist_k(const int* __restrict__ head,
                       const int* __restrict__ mcol,
                       const int* __restrict__ mrow,
                       int* __restrict__ eh, int* __restrict__ ch, int* __restrict__ rh) {
    for (int i = blockIdx.x * blockDim.x + threadIdx.x; i < NTOT;
         i += gridDim.x * blockDim.x) {
        if (i < N_EDGES) atomicAdd(&eh[head[i]], 1);
        else if (i < N_EDGES + N_INTER) atomicAdd(&ch[mcol[i - N_EDGES]], 1);
        else atomicAdd(&rh[mrow[i - N_EDGES - N_INTER]], 1);
    }
}

// ---- scan stage A: per-chunk partial sums (hist arrays are contiguous) ----
__global__ void scanA_k(const int* __restrict__ hist_all,  // e|c|r contiguous
                        int* __restrict__ blk_sums) {
    __shared__ int ss[256];
    int b = blockIdx.x, t = threadIdx.x;
    int base = b * CHUNK;
    int sum = 0;
    if (t < 250) {
        int g = base + t * THR_OWN;
#pragma unroll
        for (int j = 0; j < THR_OWN; ++j) sum += hist_all[g + j];
    }
    ss[t] = sum;
    __syncthreads();
    for (int off = 128; off > 0; off >>= 1) {
        if (t < off) ss[t] += ss[t + off];
        __syncthreads();
    }
    if (t == 0) blk_sums[b] = ss[0];
}

// ---- scan stage B: single small block scans 320 partials, segment-reset ----
__global__ void scanB_k(int* __restrict__ blk_sums, int* __restrict__ blk_off,
                        int* __restrict__ e_starts, int* __restrict__ c_starts,
                        int* __restrict__ r_starts) {
    __shared__ int ss[512];
    int t = threadIdx.x;
    ss[t] = (t < NBLK_TOT) ? blk_sums[t] : 0;
    __syncthreads();
    for (int off = 1; off < 512; off <<= 1) {
        int v = (t >= off) ? ss[t - off] : 0;
        __syncthreads();
        ss[t] += v;   // inclusive scan
        __syncthreads();
    }
    if (t < NBLK_TOT) {
        int excl = (t == 0) ? 0 : ss[t - 1];
        int segstart_excl;
        if (t < NBLK_E) segstart_excl = 0;
        else if (t < NBLK_E + NBLK_C) segstart_excl = ss[NBLK_E - 1];
        else segstart_excl = ss[NBLK_E + NBLK_C - 1];
        blk_off[t] = excl - segstart_excl;
    }
    if (t == 0) {
        e_starts[N_ENTITIES] = N_EDGES;
        c_starts[N_ITEMS]    = N_INTER;
        r_starts[N_USERS]    = N_INTER;
    }
}

// ---- scan stage C: re-scan chunk, write starts + curs ----
__global__ void scanC_k(const int* __restrict__ hist_all,
                        const int* __restrict__ blk_off,
                        int* __restrict__ e_starts, int* __restrict__ c_starts,
                        int* __restrict__ r_starts,
                        int* __restrict__ e_curs, int* __restrict__ c_curs,
                        int* __restrict__ r_curs) {
    __shared__ int ss[256];
    int b = blockIdx.x, t = threadIdx.x;
    int base = b * CHUNK;
    int h[THR_OWN];
    int sum = 0;
    if (t < 250) {
        int g = base + t * THR_OWN;
#pragma unroll
        for (int j = 0; j < THR_OWN; ++j) { h[j] = hist_all[g + j]; sum += h[j]; }
    }
    ss[t] = sum;
    __syncthreads();
    for (int off = 1; off < 256; off <<= 1) {
        int v = (t >= off) ? ss[t - off] : 0;
        __syncthreads();
        ss[t] += v;
        __syncthreads();
    }
    if (t < 250) {
        int run = blk_off[b] + ((t == 0) ? 0 : ss[t - 1]);
        int* s; int* c; int ebase;
        if (b < NBLK_E)               { s = e_starts; c = e_curs; ebase = base; }
        else if (b < NBLK_E + NBLK_C) { s = c_starts; c = c_curs; ebase = base - NBLK_E * CHUNK; }
        else                          { s = r_starts; c = r_curs; ebase = base - (NBLK_E + NBLK_C) * CHUNK; }
        int g = ebase + t * THR_OWN;
#pragma unroll
        for (int j = 0; j < THR_OWN; ++j) { s[g + j] = run; c[g + j] = run; run += h[j]; }
    }
}

// ---- permute, XCD-partitioned by key range to kill write amplification ----
__global__ void permute_e_k(const int* __restrict__ head, const int* __restrict__ tail,
                            const int* __restrict__ type,
                            int* __restrict__ ec, int* __restrict__ e_sorted) {
    int xcd = blockIdx.x & 7;
    int slot = blockIdx.x >> 3;
    int nslot = gridDim.x >> 3;
    int lo = xcd * (N_ENTITIES / 8);
    int hi = lo + (N_ENTITIES / 8);
    for (int i = slot * blockDim.x + threadIdx.x; i < N_EDGES;
         i += nslot * blockDim.x) {
        int h = __builtin_nontemporal_load(&head[i]);
        if (h >= lo && h < hi) {
            int pos = atomicAdd(&ec[h], 1);
            int t = __builtin_nontemporal_load(&tail[i]);
            int r = __builtin_nontemporal_load(&type[i]);
            e_sorted[pos] = t | (r << 18);   // 150K < 2^18, type < 32
        }
    }
}

__global__ void permute_i_k(const int* __restrict__ mcol, const int* __restrict__ mrow,
                            int* __restrict__ cc, int* __restrict__ rc,
                            int* __restrict__ i_srow, int* __restrict__ i_scol) {
    int xcd = blockIdx.x & 7;
    int slot = blockIdx.x >> 3;
    int nslot = gridDim.x >> 3;
    int clo = xcd * (N_ITEMS / 8), chi = clo + (N_ITEMS / 8);
    int rlo = xcd * (N_USERS / 8), rhi = rlo + (N_USERS / 8);
    for (int i = slot * blockDim.x + threadIdx.x; i < N_INTER;
         i += nslot * blockDim.x) {
        int c = __builtin_nontemporal_load(&mcol[i]);
        int r = __builtin_nontemporal_load(&mrow[i]);
        if (c >= clo && c < chi) {
            int pos = atomicAdd(&cc[c], 1);
            i_srow[pos] = r;
        }
        if (r >= rlo && r < rhi) {
            int pos = atomicAdd(&rc[r], 1);
            i_scol[pos] = c;
        }
    }
}

// ---- per-entity aggregation (gather, float2, split-wave). ----
__global__ void edge_agg_k(const float* __restrict__ ent,
                           const float* __restrict__ wrel,
                           const int* __restrict__ es,
                           const int* __restrict__ e_sorted,
                           float* __restrict__ agg,
                           float* __restrict__ ent_cur,
                           float* __restrict__ ent_res,
                           int last_hop) {
    __shared__ float2 wl2[32 * 32];   // 32 relations x 32 float2
    for (int idx = threadIdx.x; idx < 32 * 32; idx += blockDim.x)
        wl2[idx] = ((const float2*)wrel)[idx];
    __syncthreads();
    const float2* ent2 = (const float2*)ent;
    int lane = threadIdx.x & 63;
    int halfid = lane >> 5, hl = lane & 31;
    int wid = blockIdx.x * (blockDim.x >> 6) + (threadIdx.x >> 6);
    int nw = gridDim.x * (blockDim.x >> 6);
    for (int h = wid; h < N_ENTITIES; h += nw) {
        int beg = es[h], end = es[h + 1];
        float ax0 = 0.f, ay0 = 0.f, ax1 = 0.f, ay1 = 0.f;
        for (int j0 = beg; j0 < end; j0 += 64) {
            int p = (j0 + lane < end) ? e_sorted[j0 + lane] : 0;
            int m = end - j0; if (m > 64) m = 64;
            int k = 0;
            for (; k + 3 < m; k += 4) {      // uniform: k+3 <= m-1, all valid
                int p0 = __shfl(p, k + halfid, 64);
                int p1 = __shfl(p, k + 2 + halfid, 64);
                float2 e0 = ent2[(size_t)(p0 & 0x3FFFF) * 32 + hl];
                float2 w0 = wl2[((p0 >> 18) << 5) + hl];
                float2 e1 = ent2[(size_t)(p1 & 0x3FFFF) * 32 + hl];
                float2 w1 = wl2[((p1 >> 18) << 5) + hl];
                ax0 = fmaf(e0.x, w0.x, ax0); ay0 = fmaf(e0.y, w0.y, ay0);
                ax1 = fmaf(e1.x, w1.x, ax1); ay1 = fmaf(e1.y, w1.y, ay1);
            }
            for (; k < m; k += 2) {          // uniform tail (<=2 iters)
                int i0 = k + halfid;
                int p0 = __shfl(p, i0 & 63, 64);   // full-wave shfl, clamped
                if (i0 < m) {                       // predicate accumulate only
                    float2 e0 = ent2[(size_t)(p0 & 0x3FFFF) * 32 + hl];
                    float2 w0 = wl2[((p0 >> 18) << 5) + hl];
                    ax0 = fmaf(e0.x, w0.x, ax0); ay0 = fmaf(e0.y, w0.y, ay0);
                }
            }
        }
        float ax = ax0 + ax1, ay = ay0 + ay1;
        ax += __shfl_xor(ax, 32, 64);          // combine halves
        ay += __shfl_xor(ay, 32, 64);
        if (h < N_ITEMS) {
            if (halfid == 0) {
                int d = end - beg;
                float inv = 1.0f / (float)(d > 0 ? d : 1);
                float2 o; o.x = ax * inv; o.y = ay * inv;
                ((float2*)agg)[(size_t)h * 32 + hl] = o;
            }
        } else {
            // l2norm(mean) == l2norm(sum): scale-invariant
            float s = half_sum32(ax * ax + ay * ay);
            float inv = 1.0f / fmaxf(sqrtf(s), 1e-12f);
            float2 vn; vn.x = ax * inv; vn.y = ay * inv;
            size_t off = (size_t)h * 32 + hl;
            if (halfid == 0) {
                if (!last_hop) ((float2*)ent_cur)[off] = vn;
            } else {
                float2 r = ((float2*)ent_res)[off];
                r.x += vn.x; r.y += vn.y;
                ((float2*)ent_res)[off] = r;
            }
        }
    }
}

// ---- per-item interaction mean (gather, float2, split-wave, uniform) ----
__global__ void inter_agg_k(const float* __restrict__ usr,
                            const int* __restrict__ cs,
                            const int* __restrict__ i_srow,
                            float* __restrict__ iint) {
    const float2* usr2 = (const float2*)usr;
    int lane = threadIdx.x & 63;
    int halfid = lane >> 5, hl = lane & 31;
    int wid = blockIdx.x * (blockDim.x >> 6) + (threadIdx.x >> 6);
    int nw = gridDim.x * (blockDim.x >> 6);
    for (int c = wid; c < N_ITEMS; c += nw) {
        int beg = cs[c], end = cs[c + 1];
        float ax0 = 0.f, ay0 = 0.f, ax1 = 0.f, ay1 = 0.f;
        for (int j0 = beg; j0 < end; j0 += 64) {
            int p = (j0 + lane < end) ? i_srow[j0 + lane] : 0;
            int m = end - j0; if (m > 64) m = 64;
            int k = 0;
            for (; k + 3 < m; k += 4) {
                int p0 = __shfl(p, k + halfid, 64);
                int p1 = __shfl(p, k + 2 + halfid, 64);
                float2 u0 = usr2[(size_t)p0 * 32 + hl];
                float2 u1 = usr2[(size_t)p1 * 32 + hl];
                ax0 += u0.x; ay0 += u0.y; ax1 += u1.x; ay1 += u1.y;
            }
            for (; k < m; k += 2) {
                int i0 = k + halfid;
                int p0 = __shfl(p, i0 & 63, 64);
                if (i0 < m) {
                    float2 u0 = usr2[(size_t)p0 * 32 + hl];
                    ax0 += u0.x; ay0 += u0.y;
                }
            }
        }
        float ax = ax0 + ax1, ay = ay0 + ay1;
        ax += __shfl_xor(ax, 32, 64);
        ay += __shfl_xor(ay, 32, 64);
        if (halfid == 0) {
            int d = end - beg;
            float inv = 1.0f / (float)(d > 0 ? d : 1);
            float2 o; o.x = ax * inv; o.y = ay * inv;
            ((float2*)iint)[(size_t)c * 32 + hl] = o;
        }
    }
}

// ---- fuse: register-tiled LDS GEMM, y = [kg|ii] @ [g1|g2]^T ----
// One 64-item tile per block; 256 threads = 16x16; each thread computes a
// 4x4 (item x col) register tile via ds_read_b128. Norms via 16-lane
// shfl_xor reduce (full-wave, uniform). ifus may alias iint: this block is
// the only reader/writer of its tile, and all iint reads (staging) complete
// at the barrier before ifus writes.
__global__ void fuse_k(const float* __restrict__ agg,
                       const float* __restrict__ iint,
                       const float* __restrict__ g1,
                       const float* __restrict__ g2,
                       float* __restrict__ ifus,
                       float* __restrict__ ent_cur,
                       float* __restrict__ ent_res,
                       float* __restrict__ kg_res,
                       float* __restrict__ int_res) {
    __shared__ float A[FT * FPAD];   // [item][k]: k 0..63 = kg, 64..127 = ii
    __shared__ float B[64 * FPAD];   // [j][k]:    k 0..63 = g1, 64..127 = g2
    int t = threadIdx.x;
    int ibase = blockIdx.x * FT;

    // stage B (g1,g2 row-major [j][k]) and A (tile of agg|iint)
    {
        const float4* g14 = (const float4*)g1;
        const float4* g24 = (const float4*)g2;
        const float4* a4 = (const float4*)(agg + (size_t)ibase * D);
        const float4* i4 = (const float4*)(iint + (size_t)ibase * D);
        for (int idx = t; idx < 1024; idx += 256) {
            int r = idx >> 4, kq = idx & 15;
            ((float4*)&B[r * FPAD])[kq]      = g14[idx];
            ((float4*)&B[r * FPAD + 64])[kq] = g24[idx];
            ((float4*)&A[r * FPAD])[kq]      = a4[idx];   // benign OOB read on
            ((float4*)&A[r * FPAD + 64])[kq] = i4[idx];   // tail tile (ws mem)
        }
    }
    __syncthreads();

    int ti = t >> 4, tj = t & 15;   // wave = ti 0..3 x tj 0..15

    // GEMM: y[a][b] for item i = ti+16a, col j = tj+16b
    float y[4][4] = {};
    for (int k = 0; k < 128; k += 4) {
        float4 av[4], bv[4];
#pragma unroll
        for (int a = 0; a < 4; ++a) av[a] = *(const float4*)&A[(ti + 16 * a) * FPAD + k];
#pragma unroll
        for (int b = 0; b < 4; ++b) bv[b] = *(const float4*)&B[(tj + 16 * b) * FPAD + k];
#pragma unroll
        for (int a = 0; a < 4; ++a)
#pragma unroll
            for (int b = 0; b < 4; ++b) {
                y[a][b] = fmaf(av[a].x, bv[b].x, y[a][b]);
                y[a][b] = fmaf(av[a].y, bv[b].y, y[a][b]);
                y[a][b] = fmaf(av[a].z, bv[b].z, y[a][b]);
                y[a][b] = fmaf(av[a].w, bv[b].w, y[a][b]);
            }
    }

    // gate + fusion + per-item partial norms
    float fus[4][4], kg[4][4], ii[4][4];
    float sf[4], sk[4], si[4];
#pragma unroll
    for (int a = 0; a < 4; ++a) { sf[a] = 0.f; sk[a] = 0.f; si[a] = 0.f; }
#pragma unroll
    for (int a = 0; a < 4; ++a) {
        int i = ti + 16 * a;
#pragma unroll
        for (int b = 0; b < 4; ++b) {
            int j = tj + 16 * b;
            float K = A[i * FPAD + j];
            float I = A[i * FPAD + 64 + j];
            float gi = 1.0f / (1.0f + __expf(-y[a][b]));
            float f = gi * K + (1.0f - gi) * I;
            fus[a][b] = f; kg[a][b] = K; ii[a][b] = I;
            sf[a] = fmaf(f, f, sf[a]);
            sk[a] = fmaf(K, K, sk[a]);
            si[a] = fmaf(I, I, si[a]);
        }
    }
    // reduce across the 16 lanes sharing ti (contiguous lanes, offsets 1..8)
#pragma unroll
    for (int off = 1; off < 16; off <<= 1) {
#pragma unroll
        for (int a = 0; a < 4; ++a) {
            sf[a] += __shfl_xor(sf[a], off, 64);
            sk[a] += __shfl_xor(sk[a], off, 64);
            si[a] += __shfl_xor(si[a], off, 64);
        }
    }

    // write outputs (guard tail tile)
#pragma unroll
    for (int a = 0; a < 4; ++a) {
        int i = ibase + ti + 16 * a;
        if (i < N_ITEMS) {
            float nf = 1.0f / fmaxf(sqrtf(sf[a]), 1e-12f);
            float nk = 1.0f / fmaxf(sqrtf(sk[a]), 1e-12f);
            float ni = 1.0f / fmaxf(sqrtf(si[a]), 1e-12f);
#pragma unroll
            for (int b = 0; b < 4; ++b) {
                size_t o = (size_t)i * D + tj + 16 * b;
                float f = fus[a][b];
                ifus[o] = f;
                float fn = f * nf;
                ent_cur[o] = fn;
                ent_res[o] += fn;
                kg_res[o] += kg[a][b] * nk;
                int_res[o] += ii[a][b] * ni;
            }
        }
    }
}

// ---- per-user segment sum of item_fusion + l2 norm (float2, uniform) ----
__global__ void user_agg_k(const float* __restrict__ ifus,
                           const int* __restrict__ rs,
                           const int* __restrict__ i_scol,
                           float* __restrict__ usr_cur,
                           float* __restrict__ usr_res) {
    const float2* if2 = (const float2*)ifus;
    int lane = threadIdx.x & 63;
    int halfid = lane >> 5, hl = lane & 31;
    int wid = blockIdx.x * (blockDim.x >> 6) + (threadIdx.x >> 6);
    int nw = gridDim.x * (blockDim.x >> 6);
    for (int u = wid; u < N_USERS; u += nw) {
        int beg = rs[u], end = rs[u + 1];
        float ax0 = 0.f, ay0 = 0.f, ax1 = 0.f, ay1 = 0.f;
        for (int j0 = beg; j0 < end; j0 += 64) {
            int p = (j0 + lane < end) ? i_scol[j0 + lane] : 0;
            int m = end - j0; if (m > 64) m = 64;
            int k = 0;
            for (; k + 3 < m; k += 4) {
                int p0 = __shfl(p, k + halfid, 64);
                int p1 = __shfl(p, k + 2 + halfid, 64);
                float2 u0 = if2[(size_t)p0 * 32 + hl];
                float2 u1 = if2[(size_t)p1 * 32 + hl];
                ax0 += u0.x; ay0 += u0.y; ax1 += u1.x; ay1 += u1.y;
            }
            for (; k < m; k += 2) {
                int i0 = k + halfid;
                int p0 = __shfl(p, i0 & 63, 64);
                if (i0 < m) {
                    float2 u0 = if2[(size_t)p0 * 32 + hl];
                    ax0 += u0.x; ay0 += u0.y;
                }
            }
        }
        float ax = ax0 + ax1, ay = ay0 + ay1;
        ax += __shfl_xor(ax, 32, 64);
        ay += __shfl_xor(ay, 32, 64);
        float s = half_sum32(ax * ax + ay * ay);
        float inv = 1.0f / fmaxf(sqrtf(s), 1e-12f);
        float2 vn; vn.x = ax * inv; vn.y = ay * inv;
        size_t off = (size_t)u * 32 + hl;
        if (halfid == 0) {
            ((float2*)usr_cur)[off] = vn;
        } else {
            float2 r = ((float2*)usr_res)[off];
            r.x += vn.x; r.y += vn.y;
            ((float2*)usr_res)[off] = r;
        }
    }
}

extern "C" void kernel_launch(void* const* d_in, const int* in_sizes, int n_in,
                              void* d_out, int out_size, void* d_ws, size_t ws_size,
                              hipStream_t stream) {
    const float* user_emb   = (const float*)d_in[0];
    const float* entity_emb = (const float*)d_in[1];
    const float* wrel       = (const float*)d_in[2];
    const float* g1         = (const float*)d_in[3];
    const float* g2         = (const float*)d_in[4];
    const int*   edge_head  = (const int*)d_in[5];
    const int*   edge_tail  = (const int*)d_in[6];
    const int*   edge_type  = (const int*)d_in[7];
    const int*   mat_row    = (const int*)d_in[8];
    const int*   mat_col    = (const int*)d_in[9];

    const size_t ENT_SZ = (size_t)N_ENTITIES * D;  //  9.6M
    const size_t USR_SZ = (size_t)N_USERS * D;     // 12.8M
    const size_t ITM_SZ = (size_t)N_ITEMS * D;     //  3.2M

    float* out     = (float*)d_out;
    float* ent_res = out;
    float* usr_res = out + ENT_SZ;
    float* kg_res  = out + ENT_SZ + USR_SZ;
    float* int_res = out + ENT_SZ + USR_SZ + ITM_SZ;

    // workspace layout
    float* ws      = (float*)d_ws;
    float* ent_cur = ws;                        // 9.6M f
    float* usr_cur = ent_cur + ENT_SZ;          // 12.8M f
    float* agg     = usr_cur + USR_SZ;          // 3.2M f (item kg means)
    float* iint    = agg + ITM_SZ;              // 3.2M f (aliases ifus)
    float* ifus    = iint;                      // alias: staged read precedes write
    int*   e_hist  = (int*)(iint + ITM_SZ);     // 150000  } contiguous:
    int*   c_hist  = e_hist + N_ENTITIES;       //  50000  } one memset +
    int*   r_hist  = c_hist + N_ITEMS;          // 200000  } one scan input
    int*   e_starts = r_hist + N_USERS;         // 150001
    int*   c_starts = e_starts + N_ENTITIES + 1;//  50001
    int*   r_starts = c_starts + N_ITEMS + 1;   // 200001
    int*   e_curs   = r_starts + N_USERS + 1;   // 150000
    int*   c_curs   = e_curs + N_ENTITIES;      //  50000
    int*   r_curs   = c_curs + N_ITEMS;         // 200000
    int*   e_sorted = r_curs + N_USERS;         // 2,000,000 (tail | type<<18)
    int*   i_srow   = e_sorted + N_EDGES;       // 1,000,000
    int*   i_scol   = i_srow + N_INTER;         // 1,000,000
    int*   blk_sums = i_scol + N_INTER;         // 320
    int*   blk_off  = blk_sums + NBLK_TOT;      // 320

    // init outputs + histograms
    hipMemcpyAsync(ent_res, entity_emb, ENT_SZ * sizeof(float), hipMemcpyDeviceToDevice, stream);
    hipMemcpyAsync(usr_res, user_emb,   USR_SZ * sizeof(float), hipMemcpyDeviceToDevice, stream);
    hipMemsetAsync(kg_res, 0, 2 * ITM_SZ * sizeof(float), stream);
    hipMemsetAsync(e_hist, 0, (N_ENTITIES + N_ITEMS + N_USERS) * sizeof(int), stream);

    // CSR build (hop-invariant)
    hist_k<<<4096, 256, 0, stream>>>(edge_head, mat_col, mat_row, e_hist, c_hist, r_hist);
    scanA_k<<<NBLK_TOT, 256, 0, stream>>>(e_hist, blk_sums);
    scanB_k<<<1, 512, 0, stream>>>(blk_sums, blk_off, e_starts, c_starts, r_starts);
    scanC_k<<<NBLK_TOT, 256, 0, stream>>>(e_hist, blk_off,
                                          e_starts, c_starts, r_starts,
                                          e_curs, c_curs, r_curs);
    permute_e_k<<<4096, 256, 0, stream>>>(edge_head, edge_tail, edge_type,
                                          e_curs, e_sorted);
    permute_i_k<<<4096, 256, 0, stream>>>(mat_col, mat_row,
                                          c_curs, r_curs, i_srow, i_scol);

    for (int hop = 0; hop < 2; ++hop) {
        const float* ent_src = (hop == 0) ? entity_emb : ent_cur;
        const float* usr_src = (hop == 0) ? user_emb : usr_cur;
        int last = (hop == 1);
        edge_agg_k<<<2048, 256, 0, stream>>>(ent_src, wrel, e_starts, e_sorted,
                                             agg, ent_cur, ent_res, last);
        inter_agg_k<<<2048, 256, 0, stream>>>(usr_src, c_starts, i_srow, iint);
        fuse_k<<<NTILE, 256, 0, stream>>>(agg, iint, g1, g2, ifus,
                                          ent_cur, ent_res, kg_res, int_res);
        user_agg_k<<<2048, 256, 0, stream>>>(ifus, r_starts, i_scol, usr_cur, usr_res);
    }
}

// Round 7
// 829.924 us; speedup vs baseline: 3.0472x; 1.0180x over previous
//
#include <hip/hip_runtime.h>
#include <math.h>

#define N_USERS    200000
#define N_ITEMS    50000
#define N_ENTITIES 150000
#define N_EDGES    2000000
#define N_INTER    1000000
#define D          64
#define NTOT       (N_EDGES + 2 * N_INTER)

// scan decomposition: chunks of 1250 elements, segments align to chunks
#define CHUNK      1250
#define THR_OWN    5        // 250 active threads * 5 = 1250
#define NBLK_E     120      // 150000 / 1250
#define NBLK_C     40       //  50000 / 1250
#define NBLK_R     160      // 200000 / 1250
#define NBLK_TOT   (NBLK_E + NBLK_C + NBLK_R)   // 320

// fuse GEMM tiling
#define FT    64            // items per tile
#define FPAD  132           // LDS row stride in floats (128 + 4)
#define NTILE ((N_ITEMS + FT - 1) / FT)   // 782

__device__ __forceinline__ float half_sum32(float v) {
#pragma unroll
    for (int off = 16; off > 0; off >>= 1) v += __shfl_xor(v, off, 64);
    return v;
}

// ---- CSR histogram, XCD-partitioned by key range (kills cross-XCD atomic
// line bouncing; index arrays are L3-resident so 8x re-read is cheap) ----
__global__ void hist_k(const int* __restrict__ head,
                       const int* __restrict__ mcol,
                       const int* __restrict__ mrow,
                       int* __restrict__ eh, int* __restrict__ ch, int* __restrict__ rh) {
    int xcd = blockIdx.x & 7;
    int slot = blockIdx.x >> 3;
    int nslot = gridDim.x >> 3;
    int stride = nslot * blockDim.x;
    int base = slot * blockDim.x + threadIdx.x;
    int elo = xcd * (N_ENTITIES / 8), ehi = elo + (N_ENTITIES / 8);
    for (int i = base; i < N_EDGES; i += stride) {
        int h = __builtin_nontemporal_load(&head[i]);
        if (h >= elo && h < ehi) atomicAdd(&eh[h], 1);
    }
    int clo = xcd * (N_ITEMS / 8), chi = clo + (N_ITEMS / 8);
    int rlo = xcd * (N_USERS / 8), rhi = rlo + (N_USERS / 8);
    for (int i = base; i < N_INTER; i += stride) {
        int c = __builtin_nontemporal_load(&mcol[i]);
        int r = __builtin_nontemporal_load(&mrow[i]);
        if (c >= clo && c < chi) atomicAdd(&ch[c], 1);
        if (r >= rlo && r < rhi) atomicAdd(&rh[r], 1);
    }
}

// ---- scan stage A: per-chunk partial sums (hist arrays are contiguous) ----
__global__ void scanA_k(const int* __restrict__ hist_all,  // e|c|r contiguous
                        int* __restrict__ blk_sums) {
    __shared__ int ss[256];
    int b = blockIdx.x, t = threadIdx.x;
    int base = b * CHUNK;
    int sum = 0;
    if (t < 250) {
        int g = base + t * THR_OWN;
#pragma unroll
        for (int j = 0; j < THR_OWN; ++j) sum += hist_all[g + j];
    }
    ss[t] = sum;
    __syncthreads();
    for (int off = 128; off > 0; off >>= 1) {
        if (t < off) ss[t] += ss[t + off];
        __syncthreads();
    }
    if (t == 0) blk_sums[b] = ss[0];
}

// ---- scan stage B: single small block scans 320 partials, segment-reset ----
__global__ void scanB_k(int* __restrict__ blk_sums, int* __restrict__ blk_off,
                        int* __restrict__ e_starts, int* __restrict__ c_starts,
                        int* __restrict__ r_starts) {
    __shared__ int ss[512];
    int t = threadIdx.x;
    ss[t] = (t < NBLK_TOT) ? blk_sums[t] : 0;
    __syncthreads();
    for (int off = 1; off < 512; off <<= 1) {
        int v = (t >= off) ? ss[t - off] : 0;
        __syncthreads();
        ss[t] += v;   // inclusive scan
        __syncthreads();
    }
    if (t < NBLK_TOT) {
        int excl = (t == 0) ? 0 : ss[t - 1];
        int segstart_excl;
        if (t < NBLK_E) segstart_excl = 0;
        else if (t < NBLK_E + NBLK_C) segstart_excl = ss[NBLK_E - 1];
        else segstart_excl = ss[NBLK_E + NBLK_C - 1];
        blk_off[t] = excl - segstart_excl;
    }
    if (t == 0) {
        e_starts[N_ENTITIES] = N_EDGES;
        c_starts[N_ITEMS]    = N_INTER;
        r_starts[N_USERS]    = N_INTER;
    }
}

// ---- scan stage C: re-scan chunk, write starts + curs ----
__global__ void scanC_k(const int* __restrict__ hist_all,
                        const int* __restrict__ blk_off,
                        int* __restrict__ e_starts, int* __restrict__ c_starts,
                        int* __restrict__ r_starts,
                        int* __restrict__ e_curs, int* __restrict__ c_curs,
                        int* __restrict__ r_curs) {
    __shared__ int ss[256];
    int b = blockIdx.x, t = threadIdx.x;
    int base = b * CHUNK;
    int h[THR_OWN];
    int sum = 0;
    if (t < 250) {
        int g = base + t * THR_OWN;
#pragma unroll
        for (int j = 0; j < THR_OWN; ++j) { h[j] = hist_all[g + j]; sum += h[j]; }
    }
    ss[t] = sum;
    __syncthreads();
    for (int off = 1; off < 256; off <<= 1) {
        int v = (t >= off) ? ss[t - off] : 0;
        __syncthreads();
        ss[t] += v;
        __syncthreads();
    }
    if (t < 250) {
        int run = blk_off[b] + ((t == 0) ? 0 : ss[t - 1]);
        int* s; int* c; int ebase;
        if (b < NBLK_E)               { s = e_starts; c = e_curs; ebase = base; }
        else if (b < NBLK_E + NBLK_C) { s = c_starts; c = c_curs; ebase = base - NBLK_E * CHUNK; }
        else                          { s = r_starts; c = r_curs; ebase = base - (NBLK_E + NBLK_C) * CHUNK; }
        int g = ebase + t * THR_OWN;
#pragma unroll
        for (int j = 0; j < THR_OWN; ++j) { s[g + j] = run; c[g + j] = run; run += h[j]; }
    }
}

// ---- permute, XCD-partitioned by key range to kill write amplification ----
__global__ void permute_e_k(const int* __restrict__ head, const int* __restrict__ tail,
                            const int* __restrict__ type,
                            int* __restrict__ ec, int* __restrict__ e_sorted) {
    int xcd = blockIdx.x & 7;
    int slot = blockIdx.x >> 3;
    int nslot = gridDim.x >> 3;
    int lo = xcd * (N_ENTITIES / 8);
    int hi = lo + (N_ENTITIES / 8);
    for (int i = slot * blockDim.x + threadIdx.x; i < N_EDGES;
         i += nslot * blockDim.x) {
        int h = __builtin_nontemporal_load(&head[i]);
        if (h >= lo && h < hi) {
            int pos = atomicAdd(&ec[h], 1);
            int t = __builtin_nontemporal_load(&tail[i]);
            int r = __builtin_nontemporal_load(&type[i]);
            e_sorted[pos] = t | (r << 18);   // 150K < 2^18, type < 32
        }
    }
}

__global__ void permute_i_k(const int* __restrict__ mcol, const int* __restrict__ mrow,
                            int* __restrict__ cc, int* __restrict__ rc,
                            int* __restrict__ i_srow, int* __restrict__ i_scol) {
    int xcd = blockIdx.x & 7;
    int slot = blockIdx.x >> 3;
    int nslot = gridDim.x >> 3;
    int clo = xcd * (N_ITEMS / 8), chi = clo + (N_ITEMS / 8);
    int rlo = xcd * (N_USERS / 8), rhi = rlo + (N_USERS / 8);
    for (int i = slot * blockDim.x + threadIdx.x; i < N_INTER;
         i += nslot * blockDim.x) {
        int c = __builtin_nontemporal_load(&mcol[i]);
        int r = __builtin_nontemporal_load(&mrow[i]);
        if (c >= clo && c < chi) {
            int pos = atomicAdd(&cc[c], 1);
            i_srow[pos] = r;
        }
        if (r >= rlo && r < rhi) {
            int pos = atomicAdd(&rc[r], 1);
            i_scol[pos] = c;
        }
    }
}

// ---- per-entity aggregation (gather, float2, split-wave). ----
// hop0 (first=1): ent_res = entity_emb + vn (pure store, folds the init copy)
// hop1 (last):    ent_res += vn
__global__ void edge_agg_k(const float* __restrict__ ent,
                           const float* __restrict__ wrel,
                           const int* __restrict__ es,
                           const int* __restrict__ e_sorted,
                           float* __restrict__ agg,
                           float* __restrict__ ent_cur,
                           float* __restrict__ ent_res,
                           int first) {
    __shared__ float2 wl2[32 * 32];   // 32 relations x 32 float2
    for (int idx = threadIdx.x; idx < 32 * 32; idx += blockDim.x)
        wl2[idx] = ((const float2*)wrel)[idx];
    __syncthreads();
    const float2* ent2 = (const float2*)ent;
    int lane = threadIdx.x & 63;
    int halfid = lane >> 5, hl = lane & 31;
    int wid = blockIdx.x * (blockDim.x >> 6) + (threadIdx.x >> 6);
    int nw = gridDim.x * (blockDim.x >> 6);
    for (int h = wid; h < N_ENTITIES; h += nw) {
        int beg = es[h], end = es[h + 1];
        float ax0 = 0.f, ay0 = 0.f, ax1 = 0.f, ay1 = 0.f;
        for (int j0 = beg; j0 < end; j0 += 64) {
            int p = (j0 + lane < end) ? e_sorted[j0 + lane] : 0;
            int m = end - j0; if (m > 64) m = 64;
            int k = 0;
            for (; k + 3 < m; k += 4) {      // uniform: k+3 <= m-1, all valid
                int p0 = __shfl(p, k + halfid, 64);
                int p1 = __shfl(p, k + 2 + halfid, 64);
                float2 e0 = ent2[(size_t)(p0 & 0x3FFFF) * 32 + hl];
                float2 w0 = wl2[((p0 >> 18) << 5) + hl];
                float2 e1 = ent2[(size_t)(p1 & 0x3FFFF) * 32 + hl];
                float2 w1 = wl2[((p1 >> 18) << 5) + hl];
                ax0 = fmaf(e0.x, w0.x, ax0); ay0 = fmaf(e0.y, w0.y, ay0);
                ax1 = fmaf(e1.x, w1.x, ax1); ay1 = fmaf(e1.y, w1.y, ay1);
            }
            for (; k < m; k += 2) {          // uniform tail (<=2 iters)
                int i0 = k + halfid;
                int p0 = __shfl(p, i0 & 63, 64);   // full-wave shfl, clamped
                if (i0 < m) {                       // predicate accumulate only
                    float2 e0 = ent2[(size_t)(p0 & 0x3FFFF) * 32 + hl];
                    float2 w0 = wl2[((p0 >> 18) << 5) + hl];
                    ax0 = fmaf(e0.x, w0.x, ax0); ay0 = fmaf(e0.y, w0.y, ay0);
                }
            }
        }
        float ax = ax0 + ax1, ay = ay0 + ay1;
        ax += __shfl_xor(ax, 32, 64);          // combine halves
        ay += __shfl_xor(ay, 32, 64);
        if (h < N_ITEMS) {
            if (halfid == 0) {
                int d = end - beg;
                float inv = 1.0f / (float)(d > 0 ? d : 1);
                float2 o; o.x = ax * inv; o.y = ay * inv;
                ((float2*)agg)[(size_t)h * 32 + hl] = o;
            }
        } else {
            // l2norm(mean) == l2norm(sum): scale-invariant
            float s = half_sum32(ax * ax + ay * ay);
            float inv = 1.0f / fmaxf(sqrtf(s), 1e-12f);
            float2 vn; vn.x = ax * inv; vn.y = ay * inv;
            size_t off = (size_t)h * 32 + hl;
            if (first) {
                if (halfid == 0) ((float2*)ent_cur)[off] = vn;
                else {
                    float2 base = ent2[off];   // ent == entity_emb on hop0
                    base.x += vn.x; base.y += vn.y;
                    ((float2*)ent_res)[off] = base;
                }
            } else {
                if (halfid == 1) {
                    float2 r = ((float2*)ent_res)[off];
                    r.x += vn.x; r.y += vn.y;
                    ((float2*)ent_res)[off] = r;
                }
            }
        }
    }
}

// ---- per-item interaction mean (gather, float2, split-wave, uniform) ----
__global__ void inter_agg_k(const float* __restrict__ usr,
                            const int* __restrict__ cs,
                            const int* __restrict__ i_srow,
                            float* __restrict__ iint) {
    const float2* usr2 = (const float2*)usr;
    int lane = threadIdx.x & 63;
    int halfid = lane >> 5, hl = lane & 31;
    int wid = blockIdx.x * (blockDim.x >> 6) + (threadIdx.x >> 6);
    int nw = gridDim.x * (blockDim.x >> 6);
    for (int c = wid; c < N_ITEMS; c += nw) {
        int beg = cs[c], end = cs[c + 1];
        float ax0 = 0.f, ay0 = 0.f, ax1 = 0.f, ay1 = 0.f;
        for (int j0 = beg; j0 < end; j0 += 64) {
            int p = (j0 + lane < end) ? i_srow[j0 + lane] : 0;
            int m = end - j0; if (m > 64) m = 64;
            int k = 0;
            for (; k + 3 < m; k += 4) {
                int p0 = __shfl(p, k + halfid, 64);
                int p1 = __shfl(p, k + 2 + halfid, 64);
                float2 u0 = usr2[(size_t)p0 * 32 + hl];
                float2 u1 = usr2[(size_t)p1 * 32 + hl];
                ax0 += u0.x; ay0 += u0.y; ax1 += u1.x; ay1 += u1.y;
            }
            for (; k < m; k += 2) {
                int i0 = k + halfid;
                int p0 = __shfl(p, i0 & 63, 64);
                if (i0 < m) {
                    float2 u0 = usr2[(size_t)p0 * 32 + hl];
                    ax0 += u0.x; ay0 += u0.y;
                }
            }
        }
        float ax = ax0 + ax1, ay = ay0 + ay1;
        ax += __shfl_xor(ax, 32, 64);
        ay += __shfl_xor(ay, 32, 64);
        if (halfid == 0) {
            int d = end - beg;
            float inv = 1.0f / (float)(d > 0 ? d : 1);
            float2 o; o.x = ax * inv; o.y = ay * inv;
            ((float2*)iint)[(size_t)c * 32 + hl] = o;
        }
    }
}

// ---- fuse: register-tiled LDS GEMM, y = [kg|ii] @ [g1|g2]^T ----
// hop0 (first=1): ent_res = ent0 + fn; kg_res = kg*nk; int_res = ii*ni
// hop1:           all three +=
__global__ void fuse_k(const float* __restrict__ agg,
                       const float* __restrict__ iint,
                       const float* __restrict__ g1,
                       const float* __restrict__ g2,
                       const float* __restrict__ ent0,
                       float* __restrict__ ifus,
                       float* __restrict__ ent_cur,
                       float* __restrict__ ent_res,
                       float* __restrict__ kg_res,
                       float* __restrict__ int_res,
                       int first) {
    __shared__ float A[FT * FPAD];   // [item][k]: k 0..63 = kg, 64..127 = ii
    __shared__ float B[64 * FPAD];   // [j][k]:    k 0..63 = g1, 64..127 = g2
    int t = threadIdx.x;
    int ibase = blockIdx.x * FT;

    // stage B (g1,g2 row-major [j][k]) and A (tile of agg|iint)
    {
        const float4* g14 = (const float4*)g1;
        const float4* g24 = (const float4*)g2;
        const float4* a4 = (const float4*)(agg + (size_t)ibase * D);
        const float4* i4 = (const float4*)(iint + (size_t)ibase * D);
        for (int idx = t; idx < 1024; idx += 256) {
            int r = idx >> 4, kq = idx & 15;
            ((float4*)&B[r * FPAD])[kq]      = g14[idx];
            ((float4*)&B[r * FPAD + 64])[kq] = g24[idx];
            ((float4*)&A[r * FPAD])[kq]      = a4[idx];   // benign OOB read on
            ((float4*)&A[r * FPAD + 64])[kq] = i4[idx];   // tail tile (ws mem)
        }
    }
    __syncthreads();

    int ti = t >> 4, tj = t & 15;   // wave = ti 0..3 x tj 0..15

    // GEMM: y[a][b] for item i = ti+16a, col j = tj+16b
    float y[4][4] = {};
    for (int k = 0; k < 128; k += 4) {
        float4 av[4], bv[4];
#pragma unroll
        for (int a = 0; a < 4; ++a) av[a] = *(const float4*)&A[(ti + 16 * a) * FPAD + k];
#pragma unroll
        for (int b = 0; b < 4; ++b) bv[b] = *(const float4*)&B[(tj + 16 * b) * FPAD + k];
#pragma unroll
        for (int a = 0; a < 4; ++a)
#pragma unroll
            for (int b = 0; b < 4; ++b) {
                y[a][b] = fmaf(av[a].x, bv[b].x, y[a][b]);
                y[a][b] = fmaf(av[a].y, bv[b].y, y[a][b]);
                y[a][b] = fmaf(av[a].z, bv[b].z, y[a][b]);
                y[a][b] = fmaf(av[a].w, bv[b].w, y[a][b]);
            }
    }

    // gate + fusion + per-item partial norms
    float fus[4][4], kg[4][4], ii[4][4];
    float sf[4], sk[4], si[4];
#pragma unroll
    for (int a = 0; a < 4; ++a) { sf[a] = 0.f; sk[a] = 0.f; si[a] = 0.f; }
#pragma unroll
    for (int a = 0; a < 4; ++a) {
        int i = ti + 16 * a;
#pragma unroll
        for (int b = 0; b < 4; ++b) {
            int j = tj + 16 * b;
            float K = A[i * FPAD + j];
            float I = A[i * FPAD + 64 + j];
            float gi = 1.0f / (1.0f + __expf(-y[a][b]));
            float f = gi * K + (1.0f - gi) * I;
            fus[a][b] = f; kg[a][b] = K; ii[a][b] = I;
            sf[a] = fmaf(f, f, sf[a]);
            sk[a] = fmaf(K, K, sk[a]);
            si[a] = fmaf(I, I, si[a]);
        }
    }
    // reduce across the 16 lanes sharing ti
#pragma unroll
    for (int off = 1; off < 16; off <<= 1) {
#pragma unroll
        for (int a = 0; a < 4; ++a) {
            sf[a] += __shfl_xor(sf[a], off, 64);
            sk[a] += __shfl_xor(sk[a], off, 64);
            si[a] += __shfl_xor(si[a], off, 64);
        }
    }

    // write outputs (guard tail tile)
#pragma unroll
    for (int a = 0; a < 4; ++a) {
        int i = ibase + ti + 16 * a;
        if (i < N_ITEMS) {
            float nf = 1.0f / fmaxf(sqrtf(sf[a]), 1e-12f);
            float nk = 1.0f / fmaxf(sqrtf(sk[a]), 1e-12f);
            float ni = 1.0f / fmaxf(sqrtf(si[a]), 1e-12f);
#pragma unroll
            for (int b = 0; b < 4; ++b) {
                size_t o = (size_t)i * D + tj + 16 * b;
                float f = fus[a][b];
                ifus[o] = f;
                float fn = f * nf;
                ent_cur[o] = fn;
                if (first) {
                    ent_res[o] = ent0[o] + fn;
                    kg_res[o]  = kg[a][b] * nk;
                    int_res[o] = ii[a][b] * ni;
                } else {
                    ent_res[o] += fn;
                    kg_res[o]  += kg[a][b] * nk;
                    int_res[o] += ii[a][b] * ni;
                }
            }
        }
    }
}

// ---- per-user segment sum of item_fusion + l2 norm (float2, uniform) ----
// hop0: usr_res = user_emb + vn (pure store); hop1: +=
__global__ void user_agg_k(const float* __restrict__ ifus,
                           const int* __restrict__ rs,
                           const int* __restrict__ i_scol,
                           const float* __restrict__ usr0,
                           float* __restrict__ usr_cur,
                           float* __restrict__ usr_res,
                           int first) {
    const float2* if2 = (const float2*)ifus;
    const float2* u02 = (const float2*)usr0;
    int lane = threadIdx.x & 63;
    int halfid = lane >> 5, hl = lane & 31;
    int wid = blockIdx.x * (blockDim.x >> 6) + (threadIdx.x >> 6);
    int nw = gridDim.x * (blockDim.x >> 6);
    for (int u = wid; u < N_USERS; u += nw) {
        int beg = rs[u], end = rs[u + 1];
        float ax0 = 0.f, ay0 = 0.f, ax1 = 0.f, ay1 = 0.f;
        for (int j0 = beg; j0 < end; j0 += 64) {
            int p = (j0 + lane < end) ? i_scol[j0 + lane] : 0;
            int m = end - j0; if (m > 64) m = 64;
            int k = 0;
            for (; k + 3 < m; k += 4) {
                int p0 = __shfl(p, k + halfid, 64);
                int p1 = __shfl(p, k + 2 + halfid, 64);
                float2 u0 = if2[(size_t)p0 * 32 + hl];
                float2 u1 = if2[(size_t)p1 * 32 + hl];
                ax0 += u0.x; ay0 += u0.y; ax1 += u1.x; ay1 += u1.y;
            }
            for (; k < m; k += 2) {
                int i0 = k + halfid;
                int p0 = __shfl(p, i0 & 63, 64);
                if (i0 < m) {
                    float2 u0 = if2[(size_t)p0 * 32 + hl];
                    ax0 += u0.x; ay0 += u0.y;
                }
            }
        }
        float ax = ax0 + ax1, ay = ay0 + ay1;
        ax += __shfl_xor(ax, 32, 64);
        ay += __shfl_xor(ay, 32, 64);
        float s = half_sum32(ax * ax + ay * ay);
        float inv = 1.0f / fmaxf(sqrtf(s), 1e-12f);
        float2 vn; vn.x = ax * inv; vn.y = ay * inv;
        size_t off = (size_t)u * 32 + hl;
        if (halfid == 0) {
            ((float2*)usr_cur)[off] = vn;
        } else if (first) {
            float2 b = u02[off];
            b.x += vn.x; b.y += vn.y;
            ((float2*)usr_res)[off] = b;
        } else {
            float2 r = ((float2*)usr_res)[off];
            r.x += vn.x; r.y += vn.y;
            ((float2*)usr_res)[off] = r;
        }
    }
}

extern "C" void kernel_launch(void* const* d_in, const int* in_sizes, int n_in,
                              void* d_out, int out_size, void* d_ws, size_t ws_size,
                              hipStream_t stream) {
    const float* user_emb   = (const float*)d_in[0];
    const float* entity_emb = (const float*)d_in[1];
    const float* wrel       = (const float*)d_in[2];
    const float* g1         = (const float*)d_in[3];
    const float* g2         = (const float*)d_in[4];
    const int*   edge_head  = (const int*)d_in[5];
    const int*   edge_tail  = (const int*)d_in[6];
    const int*   edge_type  = (const int*)d_in[7];
    const int*   mat_row    = (const int*)d_in[8];
    const int*   mat_col    = (const int*)d_in[9];

    const size_t ENT_SZ = (size_t)N_ENTITIES * D;  //  9.6M
    const size_t USR_SZ = (size_t)N_USERS * D;     // 12.8M
    const size_t ITM_SZ = (size_t)N_ITEMS * D;     //  3.2M

    float* out     = (float*)d_out;
    float* ent_res = out;
    float* usr_res = out + ENT_SZ;
    float* kg_res  = out + ENT_SZ + USR_SZ;
    float* int_res = out + ENT_SZ + USR_SZ + ITM_SZ;

    // workspace layout
    float* ws      = (float*)d_ws;
    float* ent_cur = ws;                        // 9.6M f
    float* usr_cur = ent_cur + ENT_SZ;          // 12.8M f
    float* agg     = usr_cur + USR_SZ;          // 3.2M f (item kg means)
    float* iint    = agg + ITM_SZ;              // 3.2M f (aliases ifus)
    float* ifus    = iint;                      // alias: staged read precedes write
    int*   e_hist  = (int*)(iint + ITM_SZ);     // 150000  } contiguous:
    int*   c_hist  = e_hist + N_ENTITIES;       //  50000  } one memset +
    int*   r_hist  = c_hist + N_ITEMS;          // 200000  } one scan input
    int*   e_starts = r_hist + N_USERS;         // 150001
    int*   c_starts = e_starts + N_ENTITIES + 1;//  50001
    int*   r_starts = c_starts + N_ITEMS + 1;   // 200001
    int*   e_curs   = r_starts + N_USERS + 1;   // 150000
    int*   c_curs   = e_curs + N_ENTITIES;      //  50000
    int*   r_curs   = c_curs + N_ITEMS;         // 200000
    int*   e_sorted = r_curs + N_USERS;         // 2,000,000 (tail | type<<18)
    int*   i_srow   = e_sorted + N_EDGES;       // 1,000,000
    int*   i_scol   = i_srow + N_INTER;         // 1,000,000
    int*   blk_sums = i_scol + N_INTER;         // 320
    int*   blk_off  = blk_sums + NBLK_TOT;      // 320

    // only the histograms need zeroing; all outputs are pure-stored on hop0
    hipMemsetAsync(e_hist, 0, (N_ENTITIES + N_ITEMS + N_USERS) * sizeof(int), stream);

    // CSR build (hop-invariant)
    hist_k<<<4096, 256, 0, stream>>>(edge_head, mat_col, mat_row, e_hist, c_hist, r_hist);
    scanA_k<<<NBLK_TOT, 256, 0, stream>>>(e_hist, blk_sums);
    scanB_k<<<1, 512, 0, stream>>>(blk_sums, blk_off, e_starts, c_starts, r_starts);
    scanC_k<<<NBLK_TOT, 256, 0, stream>>>(e_hist, blk_off,
                                          e_starts, c_starts, r_starts,
                                          e_curs, c_curs, r_curs);
    permute_e_k<<<4096, 256, 0, stream>>>(edge_head, edge_tail, edge_type,
                                          e_curs, e_sorted);
    permute_i_k<<<4096, 256, 0, stream>>>(mat_col, mat_row,
                                          c_curs, r_curs, i_srow, i_scol);

    for (int hop = 0; hop < 2; ++hop) {
        const float* ent_src = (hop == 0) ? entity_emb : ent_cur;
        const float* usr_src = (hop == 0) ? user_emb : usr_cur;
        int first = (hop == 0);
        edge_agg_k<<<2048, 256, 0, stream>>>(ent_src, wrel, e_starts, e_sorted,
                                             agg, ent_cur, ent_res, first);
        inter_agg_k<<<2048, 256, 0, stream>>>(usr_src, c_starts, i_srow, iint);
        fuse_k<<<NTILE, 256, 0, stream>>>(agg, iint, g1, g2, entity_emb, ifus,
                                          ent_cur, ent_res, kg_res, int_res, first);
        user_agg_k<<<2048, 256, 0, stream>>>(ifus, r_starts, i_scol, user_emb,
                                             usr_cur, usr_res, first);
    }
}